// Round 6
// baseline (3742.781 us; speedup 1.0000x reference)
//
#include <hip/hip_runtime.h>
#include <stdint.h>

#define SEQ  5120
#define DIMX 512
#define E2   2048
#define DI   1024
#define NST  16
#define DTR  32
#define KXP  64
#define LGS  2048
#define NSL  5

typedef unsigned short ushort_t;
typedef __attribute__((ext_vector_type(8))) __bf16 bf16x8;
typedef __attribute__((ext_vector_type(4))) float f32x4;

__device__ __forceinline__ float b2f(ushort_t u) {
  union { unsigned int i; float f; } v; v.i = ((unsigned int)u) << 16; return v.f;
}
__device__ __forceinline__ ushort_t f2b(float f) {
  union { float f; unsigned int i; } v; v.f = f;
  unsigned int u = v.i;
  return (ushort_t)((u + 0x7FFFu + ((u >> 16) & 1u)) >> 16);
}

#define AS1 __attribute__((address_space(1)))
#define AS3 __attribute__((address_space(3)))
__device__ __forceinline__ void glds16(const void* g, void* l) {
  __builtin_amdgcn_global_load_lds((const AS1 void*)g, (AS3 void*)l, 16, 0, 0);
}

// ---------------- workspace layout (bytes): params FIRST, big buffers last ----
#define OFF_LWB   ((size_t)256)        // 1,024
#define OFF_LNGF  ((size_t)1280)       // 2,048
#define OFF_LNBF  ((size_t)3328)       // 2,048
#define OFF_LBF   ((size_t)5376)       // 256
#define OFF_CWF   ((size_t)5632)       // 49,152
#define OFF_CBF   ((size_t)54784)      // 12,288
#define OFF_DTBF  ((size_t)67072)      // 12,288
#define OFF_ALF   ((size_t)79360)      // 196,608
#define OFF_DDF   ((size_t)275968)     // 12,288
#define OFF_WEFF  ((size_t)288256)     // 4,096
#define OFF_SC    ((size_t)292352)     // 40,960
#define OFF_DTWB  ((size_t)333312)     // 196,608
#define OFF_XPWB  ((size_t)529920)     // 393,216
#define OFF_OPWB  ((size_t)923136)     // 1,048,576
#define OFF_INWB  ((size_t)1971712)    // 2,097,152
#define OFF_XD    ((size_t)4068864)    // 3 x 5120*64*2 = 1,966,080
#define OFF_XZ    ((size_t)6034944)    // 5120*2048*2 = 20,971,520 (one batch)
#define OFF_XCT   ((size_t)27006464)   // 5120*1024*2 = 10,485,760 (one channel)
#define OFF_H     OFF_XCT              // h (one batch, 10 MB slot) nested; dead pre-conv
// total = 37,492,224 B  (~35.8 MiB)

// ---------------- K0: batched import (f32 params -> ws, bf16 or f32) ----------
struct Ent { const void* s; void* d; int n; int fmt; };  // fmt 0: dst bf16, 1: dst f32
struct Tab { Ent e[28]; };

__global__ __launch_bounds__(256) void k_import(Tab t, int cnt) {
  int id = blockIdx.y;
  if (id >= cnt) return;
  Ent E = t.e[id];
  int stride = gridDim.x * 256;
  const float* s = (const float*)E.s;
  if (E.fmt == 0) {
    ushort_t* dst = (ushort_t*)E.d;
    for (int i = blockIdx.x * 256 + threadIdx.x; i < E.n; i += stride) dst[i] = f2b(s[i]);
  } else {
    float* dst = (float*)E.d;
    for (int i = blockIdx.x * 256 + threadIdx.x; i < E.n; i += stride) dst[i] = s[i];
  }
}

// ---------------- K1: LayerNorm + ReLU -> h (bf16, one batch) -----------------
__global__ __launch_bounds__(256) void k_ln(const float* __restrict__ x,
    const float* __restrict__ gam, const float* __restrict__ bet,
    ushort_t* __restrict__ h, int b) {
  int token = blockIdx.x * 4 + (threadIdx.x >> 6);   // 0..5119
  int lane = threadIdx.x & 63;
  const float* row = x + ((size_t)b * SEQ + token) * DIMX + lane * 8;
  float4 a0 = *(const float4*)(row);
  float4 a1 = *(const float4*)(row + 4);
  float v[8] = {a0.x,a0.y,a0.z,a0.w,a1.x,a1.y,a1.z,a1.w};
  float s = 0.f, ss = 0.f;
#pragma unroll
  for (int i = 0; i < 8; i++) { s += v[i]; ss += v[i]*v[i]; }
#pragma unroll
  for (int m = 1; m < 64; m <<= 1) { s += __shfl_xor(s, m, 64); ss += __shfl_xor(ss, m, 64); }
  float mean = s * (1.f / DIMX);
  float rs = rsqrtf(ss * (1.f / DIMX) - mean * mean + 1e-5f);
  ushort_t o[8];
#pragma unroll
  for (int i = 0; i < 8; i++) {
    float y = (v[i] - mean) * rs * gam[lane*8+i] + bet[lane*8+i];
    o[i] = f2b(fmaxf(y, 0.f));
  }
  ushort_t* orow = h + (size_t)token * DIMX + lane * 8;
  *(ushort4*)(orow)     = make_ushort4(o[0],o[1],o[2],o[3]);
  *(ushort4*)(orow + 4) = make_ushort4(o[4],o[5],o[6],o[7]);
}

// ---------------- K2: in_proj GEMM (one batch): xz[l][e] = h @ W^T ------------
__global__ __launch_bounds__(256) void k_inproj(const ushort_t* __restrict__ hA,
    const ushort_t* __restrict__ Wb, ushort_t* __restrict__ xz) {
  __shared__ ushort_t As[128*32];
  __shared__ ushort_t Bs[128*32];
  const int tid = threadIdx.x;
  const int w = tid >> 6, lane = tid & 63;
  const int wr = w >> 1, wc = w & 1;
  const int m0 = blockIdx.x * 128, n0 = blockIdx.y * 128;
  const int lrow = lane & 15, lko = (lane >> 4) * 8;
  f32x4 acc[4][4];
#pragma unroll
  for (int i = 0; i < 4; i++)
#pragma unroll
    for (int j = 0; j < 4; j++) acc[i][j] = (f32x4){0.f,0.f,0.f,0.f};
  for (int k0 = 0; k0 < DIMX; k0 += 32) {
    __syncthreads();
#pragma unroll
    for (int r = 0; r < 2; r++) {
      int e = r * 256 + tid;
      int row = e >> 2, seg = e & 3;
      glds16(hA + (size_t)(m0 + row) * DIMX + k0 + seg * 8, &As[row*32 + seg*8]);
      glds16(Wb + (size_t)(n0 + row) * DIMX + k0 + seg * 8, &Bs[row*32 + seg*8]);
    }
    __syncthreads();
    bf16x8 aF[4], bF[4];
#pragma unroll
    for (int i = 0; i < 4; i++)
      aF[i] = *(const bf16x8*)&As[(wr*64 + i*16 + lrow)*32 + lko];
#pragma unroll
    for (int j = 0; j < 4; j++)
      bF[j] = *(const bf16x8*)&Bs[(wc*64 + j*16 + lrow)*32 + lko];
#pragma unroll
    for (int i = 0; i < 4; i++)
#pragma unroll
      for (int j = 0; j < 4; j++)
        acc[i][j] = __builtin_amdgcn_mfma_f32_16x16x32_bf16(aF[i], bF[j], acc[i][j], 0, 0, 0);
  }
#pragma unroll
  for (int i = 0; i < 4; i++)
#pragma unroll
    for (int j = 0; j < 4; j++)
#pragma unroll
      for (int r = 0; r < 4; r++) {
        int m = m0 + wr*64 + i*16 + (lane>>4)*4 + r;
        int n = n0 + wc*64 + j*16 + lrow;
        xz[(size_t)m * E2 + n] = f2b(acc[i][j][r]);
      }
}

// ---------------- K4: causal depthwise conv + silu -> xcT[t][d] (one br) ------
__global__ __launch_bounds__(256) void k_conv(const ushort_t* __restrict__ xz,
    const float* __restrict__ cw, const float* __restrict__ cb,
    ushort_t* __restrict__ xcT, int br) {
  __shared__ ushort_t xs[67][64];
  int t0 = blockIdx.x * 64, d0 = blockIdx.y * 64;
  int tid = threadIdx.x, col = tid & 63, rg = tid >> 6;
#pragma unroll
  for (int i = 0; i < 17; i++) {
    int row = rg + i * 4;
    if (row < 67) {
      int tau = t0 - 3 + row;
      ushort_t val = 0;
      if (tau >= 0) {
        int l = (br == 0) ? tau : (br == 1) ? (SEQ - 1 - tau)
                                            : ((tau % NSL) * 1024 + tau / NSL);
        val = xz[(size_t)l * E2 + d0 + col];
      }
      xs[row][col] = val;
    }
  }
  __syncthreads();
  int d = d0 + col;
  float w0 = cw[d*4+0], w1 = cw[d*4+1], w2 = cw[d*4+2], w3 = cw[d*4+3];
  float bias = cb[d];
#pragma unroll
  for (int i = 0; i < 16; i++) {
    int ti = rg + i * 4;
    float a = bias + w0*b2f(xs[ti][col]) + w1*b2f(xs[ti+1][col])
                   + w2*b2f(xs[ti+2][col]) + w3*b2f(xs[ti+3][col]);
    float val = a / (1.f + __expf(-a));
    xcT[(size_t)(t0 + ti) * DI + d] = f2b(val);
  }
}

// ---------------- K5: x_dbl GEMM: xd[t][64] = xcT @ xproj_w^T -----------------
__global__ __launch_bounds__(256) void k_xdbl(const ushort_t* __restrict__ xcT,
    const ushort_t* __restrict__ xpw, ushort_t* __restrict__ xd) {
  __shared__ ushort_t As[128*32];
  __shared__ ushort_t Bs[64*32];
  int t0 = blockIdx.x * 128;
  int tid = threadIdx.x, w = tid >> 6, lane = tid & 63;
  int wr = w >> 1, wc = w & 1;
  int lrow = lane & 15, lko = (lane >> 4) * 8;
  f32x4 acc[4][2];
#pragma unroll
  for (int i = 0; i < 4; i++) { acc[i][0] = (f32x4){0.f,0.f,0.f,0.f}; acc[i][1] = (f32x4){0.f,0.f,0.f,0.f}; }
  for (int k0 = 0; k0 < DI; k0 += 32) {
    __syncthreads();
#pragma unroll
    for (int r = 0; r < 2; r++) {
      int e = r * 256 + tid;
      int row = e >> 2, seg = e & 3;
      glds16(xcT + (size_t)(t0 + row) * DI + k0 + seg * 8, &As[row*32 + seg*8]);
    }
    { int row = tid >> 2, seg = tid & 3;
      glds16(xpw + (size_t)row * DI + k0 + seg * 8, &Bs[row*32 + seg*8]); }
    __syncthreads();
    bf16x8 aF[4], bF[2];
#pragma unroll
    for (int i = 0; i < 4; i++)
      aF[i] = *(const bf16x8*)&As[(wr*64 + i*16 + lrow)*32 + lko];
#pragma unroll
    for (int j = 0; j < 2; j++)
      bF[j] = *(const bf16x8*)&Bs[(wc*32 + j*16 + lrow)*32 + lko];
#pragma unroll
    for (int i = 0; i < 4; i++)
#pragma unroll
      for (int j = 0; j < 2; j++)
        acc[i][j] = __builtin_amdgcn_mfma_f32_16x16x32_bf16(aF[i], bF[j], acc[i][j], 0, 0, 0);
  }
#pragma unroll
  for (int i = 0; i < 4; i++)
#pragma unroll
    for (int j = 0; j < 2; j++)
#pragma unroll
      for (int r = 0; r < 4; r++) {
        int t = t0 + wr*64 + i*16 + (lane>>4)*4 + r;
        int nn = wc*32 + j*16 + lrow;
        xd[(size_t)t * KXP + nn] = f2b(acc[i][j][r]);
      }
}

// ---------------- K7: fused delta + conv-u + scan + gate + scatter ------------
// grid 192: br = blockIdx.x>>6, dblk = blockIdx.x&63. One batch per launch.
// lane = (g = lane>>4 -> channel-in-wave, n = lane&15 -> state/time-slot).
__global__ __launch_bounds__(256) void k_scan(
    const ushort_t* __restrict__ xz, const ushort_t* __restrict__ xd,
    const ushort_t* __restrict__ dtwb, const float* __restrict__ dtbf,
    const float* __restrict__ alf, const float* __restrict__ ddf,
    const float* __restrict__ weff, const float* __restrict__ cwf,
    const float* __restrict__ cbf, float* __restrict__ sc, int b) {
  __shared__ __align__(16) float xdS[4][16][68];   // per-wave xd chunk, f32
  __shared__ __align__(16) float dtwS[16][36];     // block's 16 channels x 32
  __shared__ float4 valsS[4][16][4];               // [wave][step][group]
  int br = blockIdx.x >> 6, dblk = blockIdx.x & 63;
  int tid = threadIdx.x, w = tid >> 6, lane = tid & 63, g = lane >> 4, n = lane & 15;
  int dloc = w * 4 + g;
  int d = dblk * 16 + dloc;
#pragma unroll
  for (int r = 0; r < 2; r++) {
    int idx = r * 256 + tid;
    int c = idx >> 5, j = idx & 31;
    dtwS[c][j] = b2f(dtwb[(size_t)br * (DI*DTR) + (size_t)(dblk*16 + c) * DTR + j]);
  }
  __syncthreads();
  float dtb_d = dtbf[br * DI + d];
  float Ap  = -__expf(alf[br * (DI*NST) + d * NST + n]);
  float Dd  = ddf[br * DI + d];
  float wef = weff[d];
  float cw0 = cwf[br*DI*4 + d*4 + 0], cw1 = cwf[br*DI*4 + d*4 + 1];
  float cw2 = cwf[br*DI*4 + d*4 + 2], cw3 = cwf[br*DI*4 + d*4 + 3];
  float cb_d = cbf[br * DI + d];
  float hst = 0.f;
  const ushort_t* xdb = xd + (size_t)br * SEQ * KXP;
  float* srow = sc + (size_t)b * SEQ;
  int kk = lane >> 2, q = lane & 3;
  for (int t0 = 0; t0 < SEQ; t0 += 16) {
    {
      const ushort_t* rp = xdb + (size_t)(t0 + kk) * KXP + q * 16;
      ushort4 h0 = *(const ushort4*)(rp);
      ushort4 h1 = *(const ushort4*)(rp + 4);
      ushort4 h2 = *(const ushort4*)(rp + 8);
      ushort4 h3 = *(const ushort4*)(rp + 12);
      float* dst = &xdS[w][kk][q * 16];
      dst[0]=b2f(h0.x); dst[1]=b2f(h0.y); dst[2]=b2f(h0.z); dst[3]=b2f(h0.w);
      dst[4]=b2f(h1.x); dst[5]=b2f(h1.y); dst[6]=b2f(h1.z); dst[7]=b2f(h1.w);
      dst[8]=b2f(h2.x); dst[9]=b2f(h2.y); dst[10]=b2f(h2.z); dst[11]=b2f(h2.w);
      dst[12]=b2f(h3.x); dst[13]=b2f(h3.y); dst[14]=b2f(h3.z); dst[15]=b2f(h3.w);
    }
    int tau = t0 + n;
    float acc = dtb_d;
#pragma unroll
    for (int jj = 0; jj < 8; jj++) {
      float4 a  = *(const float4*)&xdS[w][n][jj * 4];
      float4 wv = *(const float4*)&dtwS[dloc][jj * 4];
      acc += a.x * wv.x + a.y * wv.y + a.z * wv.z + a.w * wv.w;
    }
    float dlt = (acc > 20.f) ? acc : log1pf(__expf(acc));
    float ua = cb_d;
#pragma unroll
    for (int k = 0; k < 4; k++) {
      int s = tau - 3 + k;
      float xv = 0.f;
      if (s >= 0) {
        int ps = (br == 0) ? s : (br == 1) ? (SEQ - 1 - s)
                               : ((s % NSL) * 1024 + s / NSL);
        xv = b2f(xz[(size_t)ps * E2 + d]);
      }
      ua = fmaf((k == 0) ? cw0 : (k == 1) ? cw1 : (k == 2) ? cw2 : cw3, xv, ua);
    }
    float u = ua / (1.f + __expf(-ua));
    int pz = (br == 0) ? tau : (br == 1) ? (SEQ - 1 - tau)
                             : ((tau % NSL) * 1024 + tau / NSL);
    float zr = b2f(xz[(size_t)pz * E2 + DI + d]);
    float z = zr / (1.f + __expf(-zr));
    float gate = z * wef;
    valsS[w][n][g] = make_float4(dlt, dlt * u, gate, Dd * u * gate);
    float accm = 0.f;
#pragma unroll
    for (int k = 0; k < 16; k++) {
      float4 v = valsS[w][k][g];
      float Bn = xdS[w][k][32 + n];
      float Cn = xdS[w][k][48 + n];
      float e = __expf(v.x * Ap);
      hst = fmaf(e, hst, v.y * Bn);
      float p = hst * Cn;
      p += __shfl_xor(p, 1, 64);
      p += __shfl_xor(p, 2, 64);
      p += __shfl_xor(p, 4, 64);
      p += __shfl_xor(p, 8, 64);
      float c = fmaf(p, v.z, v.w);
      accm = (n == k) ? c : accm;
    }
    accm += __shfl_xor(accm, 16, 64);
    accm += __shfl_xor(accm, 32, 64);
    if (lane < 16) {
      int t2 = t0 + lane;
      int po = (br == 0) ? t2 : (br == 1) ? (SEQ - 1 - t2)
                              : ((t2 & 1023) * NSL + (t2 >> 10));
      atomicAdd(&srow[po], accm);
    }
  }
}

// ---------------- K8: w_eff[d] = lin_w . out_proj_w[:,d]; zero score_acc ------
__global__ __launch_bounds__(256) void k_weff_init(const ushort_t* __restrict__ opwb,
    const ushort_t* __restrict__ lwb, float* __restrict__ weff, float* __restrict__ sc) {
  int i = blockIdx.x * 256 + threadIdx.x;
  if (i < DI) {
    float s = 0.f;
    for (int o = 0; o < DIMX; o++) s += b2f(lwb[o]) * b2f(opwb[(size_t)o * DI + i]);
    weff[i] = s;
  }
  int j = i - DI;
  if (j >= 0 && j < 2 * SEQ) sc[j] = 0.f;
}

// ---------------- K9: outputs (FLOAT32): group interp+sigmoid, individual -----
__global__ __launch_bounds__(256) void k_out(const float* __restrict__ g0,
    const float* __restrict__ g1, const float* __restrict__ g2,
    const float* __restrict__ sc, const float* __restrict__ lbf,
    float* __restrict__ out) {
  int idx = blockIdx.x * 256 + threadIdx.x;
  if (idx < 3 * SEQ) {
    int j = idx / SEQ, t = idx % SEQ;
    const float* g = (j == 0) ? g0 : (j == 1) ? g1 : g2;
    float pos = t * ((float)(LGS - 1) / (float)(SEQ - 1));
    int i0 = (int)floorf(pos);
    if (i0 < 0) i0 = 0; if (i0 > LGS - 2) i0 = LGS - 2;
    float wt = pos - (float)i0;
    float v = g[i0] * (1.f - wt) + g[i0 + 1] * wt;
    out[idx] = 1.f / (1.f + __expf(-v));
  } else if (idx < 5 * SEQ) {
    float t = sc[idx - 3 * SEQ] + lbf[0];
    out[idx] = 1.f / (1.f + __expf(-t));
  }
}

extern "C" void kernel_launch(void* const* d_in, const int* in_sizes, int n_in,
                              void* d_out, int out_size, void* d_ws, size_t ws_size,
                              hipStream_t stream) {
  char* ws = (char*)d_ws;
  ushort_t* lwb   = (ushort_t*)(ws + OFF_LWB);
  float*    lngf  = (float*)(ws + OFF_LNGF);
  float*    lnbf  = (float*)(ws + OFF_LNBF);
  float*    lbf   = (float*)(ws + OFF_LBF);
  float*    cwf   = (float*)(ws + OFF_CWF);
  float*    cbf   = (float*)(ws + OFF_CBF);
  float*    dtbf  = (float*)(ws + OFF_DTBF);
  float*    alf   = (float*)(ws + OFF_ALF);
  float*    ddf   = (float*)(ws + OFF_DDF);
  float*    weff  = (float*)(ws + OFF_WEFF);
  float*    sc    = (float*)(ws + OFF_SC);
  ushort_t* dtwb  = (ushort_t*)(ws + OFF_DTWB);
  ushort_t* xpwb  = (ushort_t*)(ws + OFF_XPWB);
  ushort_t* opwb  = (ushort_t*)(ws + OFF_OPWB);
  ushort_t* inwb  = (ushort_t*)(ws + OFF_INWB);
  ushort_t* xd    = (ushort_t*)(ws + OFF_XD);
  ushort_t* xz    = (ushort_t*)(ws + OFF_XZ);
  ushort_t* xcT   = (ushort_t*)(ws + OFF_XCT);
  ushort_t* h     = (ushort_t*)(ws + OFF_H);
  float*    OUT   = (float*)d_out;

  Tab tab;
  int c = 0;
  tab.e[c++] = {d_in[3], inwb, E2 * DIMX, 0};               // in_proj_w -> bf16
  tab.e[c++] = {d_in[4], opwb, DIMX * DI, 0};               // out_proj_w -> bf16
  tab.e[c++] = {d_in[5], lwb, DIMX, 0};                     // lin_w -> bf16
  for (int br = 0; br < 3; br++) {
    int base = 10 + br * 7;
    tab.e[c++] = {d_in[base + 2], xpwb + (size_t)br * KXP * DI, KXP * DI, 0};  // xproj_w
    tab.e[c++] = {d_in[base + 3], dtwb + (size_t)br * DI * DTR, DI * DTR, 0};  // dt_w
  }
  tab.e[c++] = {d_in[1], lngf, DIMX, 1};                    // ln_g -> f32
  tab.e[c++] = {d_in[2], lnbf, DIMX, 1};                    // ln_b -> f32
  tab.e[c++] = {d_in[6], lbf, 1, 1};                        // lin_b -> f32
  for (int br = 0; br < 3; br++) {
    int base = 10 + br * 7;
    tab.e[c++] = {d_in[base + 0], cwf + (size_t)br * DI * 4, DI * 4, 1};     // conv_w
    tab.e[c++] = {d_in[base + 1], cbf + (size_t)br * DI, DI, 1};             // conv_bias
    tab.e[c++] = {d_in[base + 4], dtbf + (size_t)br * DI, DI, 1};            // dt_bias
    tab.e[c++] = {d_in[base + 5], alf + (size_t)br * DI * NST, DI * NST, 1}; // A_log
    tab.e[c++] = {d_in[base + 6], ddf + (size_t)br * DI, DI, 1};             // D
  }

  dim3 blk(256);
  k_import<<<dim3(64, c), blk, 0, stream>>>(tab, c);
  k_weff_init<<<44, blk, 0, stream>>>(opwb, lwb, weff, sc);
  for (int b = 0; b < 2; b++) {
    k_ln<<<1280, blk, 0, stream>>>((const float*)d_in[0], lngf, lnbf, h, b);
    k_inproj<<<dim3(40, 16), blk, 0, stream>>>(h, inwb, xz);
    for (int br = 0; br < 3; br++) {
      k_conv<<<dim3(80, 16), blk, 0, stream>>>(xz, cwf + (size_t)br * DI * 4,
                                               cbf + (size_t)br * DI, xcT, br);
      k_xdbl<<<40, blk, 0, stream>>>(xcT, xpwb + (size_t)br * KXP * DI,
                                     xd + (size_t)br * SEQ * KXP);
    }
    k_scan<<<192, blk, 0, stream>>>(xz, xd, dtwb, dtbf, alf, ddf, weff,
                                    cwf, cbf, sc, b);
  }
  k_out<<<100, blk, 0, stream>>>((const float*)d_in[7], (const float*)d_in[8],
                                 (const float*)d_in[9], sc, lbf, OUT);
}

// Round 7
// 1379.206 us; speedup vs baseline: 2.7137x; 2.7137x over previous
//
#include <hip/hip_runtime.h>
#include <stdint.h>

#define SEQ  5120
#define DIMX 512
#define E2   2048
#define DI   1024
#define NST  16
#define DTR  32
#define KXP  64
#define LGS  2048
#define NSL  5
#define NSEG 8
#define SEGL 640

typedef unsigned short ushort_t;
typedef __attribute__((ext_vector_type(8))) __bf16 bf16x8;
typedef __attribute__((ext_vector_type(4))) float f32x4;

__device__ __forceinline__ float b2f(ushort_t u) {
  union { unsigned int i; float f; } v; v.i = ((unsigned int)u) << 16; return v.f;
}
__device__ __forceinline__ ushort_t f2b(float f) {
  union { float f; unsigned int i; } v; v.f = f;
  unsigned int u = v.i;
  return (ushort_t)((u + 0x7FFFu + ((u >> 16) & 1u)) >> 16);
}

#define AS1 __attribute__((address_space(1)))
#define AS3 __attribute__((address_space(3)))
__device__ __forceinline__ void glds16(const void* g, void* l) {
  __builtin_amdgcn_global_load_lds((const AS1 void*)g, (AS3 void*)l, 16, 0, 0);
}

__device__ __forceinline__ int pmap(int br, int t) {   // scan pos -> data pos
  return (br == 0) ? t : (br == 1) ? (SEQ - 1 - t) : ((t % NSL) * 1024 + t / NSL);
}
__device__ __forceinline__ int omap(int br, int t) {   // scan pos -> output pos
  return (br == 0) ? t : (br == 1) ? (SEQ - 1 - t) : ((t & 1023) * NSL + (t >> 10));
}

// ---------------- workspace layout (bytes) ------------------------------------
#define OFF_LWB   ((size_t)256)
#define OFF_LNGF  ((size_t)1280)
#define OFF_LNBF  ((size_t)3328)
#define OFF_LBF   ((size_t)5376)
#define OFF_CWF   ((size_t)5632)
#define OFF_CBF   ((size_t)54784)
#define OFF_DTBF  ((size_t)67072)
#define OFF_ALF   ((size_t)79360)
#define OFF_DDF   ((size_t)275968)
#define OFF_WEFF  ((size_t)288256)
#define OFF_SC    ((size_t)292352)
#define OFF_DTWB  ((size_t)333312)
#define OFF_XPWB  ((size_t)529920)
#define OFF_OPWB  ((size_t)923136)
#define OFF_INWB  ((size_t)1971712)
#define OFF_XD    ((size_t)4068864)    // 3 x 5120*64*2 = 1,966,080
#define OFF_XZ    ((size_t)6034944)    // 5120*2048*2 = 20,971,520 (one batch)
#define OFF_UT    ((size_t)27006464)   // 3 x 5120*1024*2 = 31,457,280
#define OFF_H     OFF_UT               // h (5 MB) nested; dead before conv
#define OFF_HLOC  ((size_t)58463744)   // 3*8*1024*16*4 = 1,572,864
#define OFF_HIN   ((size_t)60036608)   // 1,572,864
#define OFF_STOT  ((size_t)61609472)   // 3*8*1024*4 = 98,304
// total = 61,707,776 B (~58.9 MiB)

// ---------------- K0: batched import (f32 params -> ws, bf16 or f32) ----------
struct Ent { const void* s; void* d; int n; int fmt; };
struct Tab { Ent e[28]; };

__global__ __launch_bounds__(256) void k_import(Tab t, int cnt) {
  int id = blockIdx.y;
  if (id >= cnt) return;
  Ent E = t.e[id];
  int stride = gridDim.x * 256;
  const float* s = (const float*)E.s;
  if (E.fmt == 0) {
    ushort_t* dst = (ushort_t*)E.d;
    for (int i = blockIdx.x * 256 + threadIdx.x; i < E.n; i += stride) dst[i] = f2b(s[i]);
  } else {
    float* dst = (float*)E.d;
    for (int i = blockIdx.x * 256 + threadIdx.x; i < E.n; i += stride) dst[i] = s[i];
  }
}

// ---------------- K1: LayerNorm + ReLU -> h (bf16, one batch) -----------------
__global__ __launch_bounds__(256) void k_ln(const float* __restrict__ x,
    const float* __restrict__ gam, const float* __restrict__ bet,
    ushort_t* __restrict__ h, int b) {
  int token = blockIdx.x * 4 + (threadIdx.x >> 6);
  int lane = threadIdx.x & 63;
  const float* row = x + ((size_t)b * SEQ + token) * DIMX + lane * 8;
  float4 a0 = *(const float4*)(row);
  float4 a1 = *(const float4*)(row + 4);
  float v[8] = {a0.x,a0.y,a0.z,a0.w,a1.x,a1.y,a1.z,a1.w};
  float s = 0.f, ss = 0.f;
#pragma unroll
  for (int i = 0; i < 8; i++) { s += v[i]; ss += v[i]*v[i]; }
#pragma unroll
  for (int m = 1; m < 64; m <<= 1) { s += __shfl_xor(s, m, 64); ss += __shfl_xor(ss, m, 64); }
  float mean = s * (1.f / DIMX);
  float rs = rsqrtf(ss * (1.f / DIMX) - mean * mean + 1e-5f);
  ushort_t o[8];
#pragma unroll
  for (int i = 0; i < 8; i++) {
    float y = (v[i] - mean) * rs * gam[lane*8+i] + bet[lane*8+i];
    o[i] = f2b(fmaxf(y, 0.f));
  }
  ushort_t* orow = h + (size_t)token * DIMX + lane * 8;
  *(ushort4*)(orow)     = make_ushort4(o[0],o[1],o[2],o[3]);
  *(ushort4*)(orow + 4) = make_ushort4(o[4],o[5],o[6],o[7]);
}

// ---------------- K2: in_proj GEMM (one batch): xz[l][e] = h @ W^T ------------
__global__ __launch_bounds__(256) void k_inproj(const ushort_t* __restrict__ hA,
    const ushort_t* __restrict__ Wb, ushort_t* __restrict__ xz) {
  __shared__ ushort_t As[128*32];
  __shared__ ushort_t Bs[128*32];
  const int tid = threadIdx.x;
  const int w = tid >> 6, lane = tid & 63;
  const int wr = w >> 1, wc = w & 1;
  const int m0 = blockIdx.x * 128, n0 = blockIdx.y * 128;
  const int lrow = lane & 15, lko = (lane >> 4) * 8;
  f32x4 acc[4][4];
#pragma unroll
  for (int i = 0; i < 4; i++)
#pragma unroll
    for (int j = 0; j < 4; j++) acc[i][j] = (f32x4){0.f,0.f,0.f,0.f};
  for (int k0 = 0; k0 < DIMX; k0 += 32) {
    __syncthreads();
#pragma unroll
    for (int r = 0; r < 2; r++) {
      int e = r * 256 + tid;
      int row = e >> 2, seg = e & 3;
      glds16(hA + (size_t)(m0 + row) * DIMX + k0 + seg * 8, &As[row*32 + seg*8]);
      glds16(Wb + (size_t)(n0 + row) * DIMX + k0 + seg * 8, &Bs[row*32 + seg*8]);
    }
    __syncthreads();
    bf16x8 aF[4], bF[4];
#pragma unroll
    for (int i = 0; i < 4; i++)
      aF[i] = *(const bf16x8*)&As[(wr*64 + i*16 + lrow)*32 + lko];
#pragma unroll
    for (int j = 0; j < 4; j++)
      bF[j] = *(const bf16x8*)&Bs[(wc*64 + j*16 + lrow)*32 + lko];
#pragma unroll
    for (int i = 0; i < 4; i++)
#pragma unroll
      for (int j = 0; j < 4; j++)
        acc[i][j] = __builtin_amdgcn_mfma_f32_16x16x32_bf16(aF[i], bF[j], acc[i][j], 0, 0, 0);
  }
#pragma unroll
  for (int i = 0; i < 4; i++)
#pragma unroll
    for (int j = 0; j < 4; j++)
#pragma unroll
      for (int r = 0; r < 4; r++) {
        int m = m0 + wr*64 + i*16 + (lane>>4)*4 + r;
        int n = n0 + wc*64 + j*16 + lrow;
        xz[(size_t)m * E2 + n] = f2b(acc[i][j][r]);
      }
}

// ---------------- K4: causal depthwise conv + silu -> uT[br][t][d] ------------
__global__ __launch_bounds__(256) void k_conv(const ushort_t* __restrict__ xz,
    const float* __restrict__ cw, const float* __restrict__ cb,
    ushort_t* __restrict__ uT, int br) {
  __shared__ ushort_t xs[67][64];
  int t0 = blockIdx.x * 64, d0 = blockIdx.y * 64;
  int tid = threadIdx.x, col = tid & 63, rg = tid >> 6;
#pragma unroll
  for (int i = 0; i < 17; i++) {
    int row = rg + i * 4;
    if (row < 67) {
      int tau = t0 - 3 + row;
      ushort_t val = 0;
      if (tau >= 0) val = xz[(size_t)pmap(br, tau) * E2 + d0 + col];
      xs[row][col] = val;
    }
  }
  __syncthreads();
  int d = d0 + col;
  float w0 = cw[d*4+0], w1 = cw[d*4+1], w2 = cw[d*4+2], w3 = cw[d*4+3];
  float bias = cb[d];
#pragma unroll
  for (int i = 0; i < 16; i++) {
    int ti = rg + i * 4;
    float a = bias + w0*b2f(xs[ti][col]) + w1*b2f(xs[ti+1][col])
                   + w2*b2f(xs[ti+2][col]) + w3*b2f(xs[ti+3][col]);
    float val = a / (1.f + __expf(-a));
    uT[(size_t)(t0 + ti) * DI + d] = f2b(val);
  }
}

// ---------------- K5: x_dbl GEMM: xd[t][64] = uT @ xproj_w^T ------------------
__global__ __launch_bounds__(256) void k_xdbl(const ushort_t* __restrict__ uT,
    const ushort_t* __restrict__ xpw, ushort_t* __restrict__ xd) {
  __shared__ ushort_t As[128*32];
  __shared__ ushort_t Bs[64*32];
  int t0 = blockIdx.x * 128;
  int tid = threadIdx.x, w = tid >> 6, lane = tid & 63;
  int wr = w >> 1, wc = w & 1;
  int lrow = lane & 15, lko = (lane >> 4) * 8;
  f32x4 acc[4][2];
#pragma unroll
  for (int i = 0; i < 4; i++) { acc[i][0] = (f32x4){0.f,0.f,0.f,0.f}; acc[i][1] = (f32x4){0.f,0.f,0.f,0.f}; }
  for (int k0 = 0; k0 < DI; k0 += 32) {
    __syncthreads();
#pragma unroll
    for (int r = 0; r < 2; r++) {
      int e = r * 256 + tid;
      int row = e >> 2, seg = e & 3;
      glds16(uT + (size_t)(t0 + row) * DI + k0 + seg * 8, &As[row*32 + seg*8]);
    }
    { int row = tid >> 2, seg = tid & 3;
      glds16(xpw + (size_t)row * DI + k0 + seg * 8, &Bs[row*32 + seg*8]); }
    __syncthreads();
    bf16x8 aF[4], bF[2];
#pragma unroll
    for (int i = 0; i < 4; i++)
      aF[i] = *(const bf16x8*)&As[(wr*64 + i*16 + lrow)*32 + lko];
#pragma unroll
    for (int j = 0; j < 2; j++)
      bF[j] = *(const bf16x8*)&Bs[(wc*32 + j*16 + lrow)*32 + lko];
#pragma unroll
    for (int i = 0; i < 4; i++)
#pragma unroll
      for (int j = 0; j < 2; j++)
        acc[i][j] = __builtin_amdgcn_mfma_f32_16x16x32_bf16(aF[i], bF[j], acc[i][j], 0, 0, 0);
  }
#pragma unroll
  for (int i = 0; i < 4; i++)
#pragma unroll
    for (int j = 0; j < 2; j++)
#pragma unroll
      for (int r = 0; r < 4; r++) {
        int t = t0 + wr*64 + i*16 + (lane>>4)*4 + r;
        int nn = wc*32 + j*16 + lrow;
        xd[(size_t)t * KXP + nn] = f2b(acc[i][j][r]);
      }
}

// ---------------- K7a: segmented local scan -----------------------------------
// grid 1536 = br(bid>>9) x seg((bid>>6)&7) x dblk(bid&63). One batch per launch.
__global__ __launch_bounds__(256, 4) void k_scan1(
    const ushort_t* __restrict__ xz, const ushort_t* __restrict__ uTa,
    const ushort_t* __restrict__ xd, const ushort_t* __restrict__ dtwb,
    const float* __restrict__ dtbf, const float* __restrict__ alf,
    const float* __restrict__ ddf, const float* __restrict__ weff,
    float* __restrict__ sc, float* __restrict__ Hloc, float* __restrict__ Stot,
    int b) {
  __shared__ __align__(16) float xdS[4][16][68];
  __shared__ __align__(16) float dtwS[16][36];
  __shared__ float2 valsS[4][4][18];
  int bid = blockIdx.x;
  int dblk = bid & 63, seg = (bid >> 6) & 7, br = bid >> 9;
  int tid = threadIdx.x, w = tid >> 6, lane = tid & 63, g = lane >> 4, n = lane & 15;
  int dloc = w * 4 + g;
  int d = dblk * 16 + dloc;
#pragma unroll
  for (int r = 0; r < 2; r++) {
    int idx = r * 256 + tid;
    int c = idx >> 5, j = idx & 31;
    dtwS[c][j] = b2f(dtwb[(size_t)br * (DI*DTR) + (size_t)(dblk*16 + c) * DTR + j]);
  }
  __syncthreads();
  float dtb_d = dtbf[br * DI + d];
  float Ap  = -__expf(alf[br * (DI*NST) + d * NST + n]);
  float Dd  = ddf[br * DI + d];
  float wef = weff[d];
  const ushort_t* ub  = uTa + (size_t)br * SEQ * DI;
  const ushort_t* xdb = xd  + (size_t)br * SEQ * KXP;
  float* srow = sc + (size_t)b * SEQ;
  float hst = 0.f, Sacc = 0.f;
  int kk = lane >> 2, q = lane & 3;
  int tbeg = seg * SEGL;
  for (int t0 = tbeg; t0 < tbeg + SEGL; t0 += 16) {
    {
      const ushort_t* rp = xdb + (size_t)(t0 + kk) * KXP + q * 16;
      ushort4 h0 = *(const ushort4*)(rp);
      ushort4 h1 = *(const ushort4*)(rp + 4);
      ushort4 h2 = *(const ushort4*)(rp + 8);
      ushort4 h3 = *(const ushort4*)(rp + 12);
      float* dst = &xdS[w][kk][q * 16];
      dst[0]=b2f(h0.x); dst[1]=b2f(h0.y); dst[2]=b2f(h0.z); dst[3]=b2f(h0.w);
      dst[4]=b2f(h1.x); dst[5]=b2f(h1.y); dst[6]=b2f(h1.z); dst[7]=b2f(h1.w);
      dst[8]=b2f(h2.x); dst[9]=b2f(h2.y); dst[10]=b2f(h2.z); dst[11]=b2f(h2.w);
      dst[12]=b2f(h3.x); dst[13]=b2f(h3.y); dst[14]=b2f(h3.z); dst[15]=b2f(h3.w);
    }
    int tau = t0 + n;
    float acc = dtb_d;
#pragma unroll
    for (int jj = 0; jj < 8; jj++) {
      float4 a  = *(const float4*)&xdS[w][n][jj * 4];
      float4 wv = *(const float4*)&dtwS[dloc][jj * 4];
      acc += a.x * wv.x + a.y * wv.y + a.z * wv.z + a.w * wv.w;
    }
    float dlt = (acc > 20.f) ? acc : log1pf(__expf(acc));
    Sacc += dlt;
    float u = b2f(ub[(size_t)tau * DI + d]);
    float zr = b2f(xz[(size_t)pmap(br, tau) * E2 + DI + d]);
    float z = zr / (1.f + __expf(-zr));
    float gate = z * wef;
    float dug = Dd * u * gate;
    valsS[w][g][n] = make_float2(dlt, dlt * u);
    float hC[16];
#pragma unroll
    for (int k = 0; k < 16; k++) {
      float2 v = valsS[w][g][k];
      float Bn = xdS[w][k][32 + n];
      float Cn = xdS[w][k][48 + n];
      hst = fmaf(__expf(v.x * Ap), hst, v.y * Bn);
      hC[k] = hst * Cn;
    }
    // reduce-scatter over n (lane ends with sum over n of hC[lane&15])
    float a8[8], a4[4], a2[2], y;
#pragma unroll
    for (int j = 0; j < 8; j++) {
      float keep = (n & 8) ? hC[j+8] : hC[j];
      float send = (n & 8) ? hC[j]   : hC[j+8];
      a8[j] = keep + __shfl_xor(send, 8, 64);
    }
#pragma unroll
    for (int j = 0; j < 4; j++) {
      float keep = (n & 4) ? a8[j+4] : a8[j];
      float send = (n & 4) ? a8[j]   : a8[j+4];
      a4[j] = keep + __shfl_xor(send, 4, 64);
    }
#pragma unroll
    for (int j = 0; j < 2; j++) {
      float keep = (n & 2) ? a4[j+2] : a4[j];
      float send = (n & 2) ? a4[j]   : a4[j+2];
      a2[j] = keep + __shfl_xor(send, 2, 64);
    }
    {
      float keep = (n & 1) ? a2[1] : a2[0];
      float send = (n & 1) ? a2[0] : a2[1];
      y = keep + __shfl_xor(send, 1, 64);
    }
    y = fmaf(y, gate, dug);
    y += __shfl_xor(y, 16, 64);
    y += __shfl_xor(y, 32, 64);
    if (lane < 16) atomicAdd(srow + omap(br, t0 + lane), y);
  }
  Hloc[(((size_t)br * NSEG + seg) * 1024 + d) * 16 + n] = hst;
  Sacc += __shfl_xor(Sacc, 1, 64);
  Sacc += __shfl_xor(Sacc, 2, 64);
  Sacc += __shfl_xor(Sacc, 4, 64);
  Sacc += __shfl_xor(Sacc, 8, 64);
  if (n == 0) Stot[((size_t)br * NSEG + seg) * 1024 + d] = Sacc;
}

// ---------------- K7b: stitch segment states ----------------------------------
__global__ __launch_bounds__(256) void k_stitch(const float* __restrict__ Stot,
    const float* __restrict__ Hloc, const float* __restrict__ alf,
    float* __restrict__ Hin) {
  int idx = blockIdx.x * 256 + threadIdx.x;     // 49152 = 3*1024*16
  int br = idx >> 14, rem = idx & 16383, d = rem >> 4, n = rem & 15;
  float A = -__expf(alf[(size_t)br * (DI*NST) + d * NST + n]);
  float h = 0.f;
  for (int s = 0; s < NSEG; s++) {
    size_t base = ((size_t)br * NSEG + s) * 1024 + d;
    Hin[base * 16 + n] = h;
    h = __expf(A * Stot[base]) * h + Hloc[base * 16 + n];
  }
}

// ---------------- K7c: carry correction (parallel over t) ---------------------
// grid 768 = br(bid>>8) x chgrp(bid&255). wave w -> channel d = chgrp*4+w.
__global__ __launch_bounds__(256, 4) void k_scan2(
    const ushort_t* __restrict__ xz, const ushort_t* __restrict__ xd,
    const ushort_t* __restrict__ dtwb, const float* __restrict__ dtbf,
    const float* __restrict__ alf, const float* __restrict__ weff,
    const float* __restrict__ Hin, float* __restrict__ sc, int b) {
  __shared__ float red[4][72];
  int br = blockIdx.x >> 8, cg = blockIdx.x & 255;
  int tid = threadIdx.x, w = tid >> 6, lane = tid & 63;
  int d = cg * 4 + w;
  const ushort_t* dwp = dtwb + (size_t)br * (DI*DTR) + (size_t)d * DTR;
  uint4 dq0 = *(const uint4*)(dwp), dq1 = *(const uint4*)(dwp + 8),
        dq2 = *(const uint4*)(dwp + 16), dq3 = *(const uint4*)(dwp + 24);
  float dw[32];
  {
    unsigned int wds[16] = {dq0.x,dq0.y,dq0.z,dq0.w, dq1.x,dq1.y,dq1.z,dq1.w,
                            dq2.x,dq2.y,dq2.z,dq2.w, dq3.x,dq3.y,dq3.z,dq3.w};
#pragma unroll
    for (int j = 0; j < 16; j++) {
      dw[2*j]   = __uint_as_float(wds[j] << 16);
      dw[2*j+1] = __uint_as_float(wds[j] & 0xFFFF0000u);
    }
  }
  float dtb_d = dtbf[br * DI + d];
  float A_[16];
#pragma unroll
  for (int nn = 0; nn < 16; nn++)
    A_[nn] = -__expf(alf[(size_t)br * (DI*NST) + d * NST + nn]);
  float wef = weff[d];
  const ushort_t* xdb = xd + (size_t)br * SEQ * KXP;
  float* srow = sc + (size_t)b * SEQ;
  for (int seg = 1; seg < NSEG; seg++) {
    float Hn[16];
    const float* hp = Hin + (((size_t)br * NSEG + seg) * 1024 + d) * 16;
#pragma unroll
    for (int nn = 0; nn < 16; nn++) Hn[nn] = hp[nn];
    float carry = 0.f;
    for (int w0 = seg * SEGL; w0 < seg * SEGL + SEGL; w0 += 64) {
      int t = w0 + lane;
      const ushort_t* rp = xdb + (size_t)t * KXP;
      uint4 q0 = *(const uint4*)(rp),      q1 = *(const uint4*)(rp + 8),
            q2 = *(const uint4*)(rp + 16), q3 = *(const uint4*)(rp + 24);
      uint4 c0 = *(const uint4*)(rp + 48), c1 = *(const uint4*)(rp + 56);
      float acc = dtb_d;
      {
        unsigned int wds[16] = {q0.x,q0.y,q0.z,q0.w, q1.x,q1.y,q1.z,q1.w,
                                q2.x,q2.y,q2.z,q2.w, q3.x,q3.y,q3.z,q3.w};
#pragma unroll
        for (int j = 0; j < 16; j++) {
          acc = fmaf(__uint_as_float(wds[j] << 16),        dw[2*j],   acc);
          acc = fmaf(__uint_as_float(wds[j] & 0xFFFF0000u), dw[2*j+1], acc);
        }
      }
      float dlt = (acc > 20.f) ? acc : log1pf(__expf(acc));
      // inclusive prefix sum over 64 lanes
      float S = dlt;
#pragma unroll
      for (int ofs = 1; ofs < 64; ofs <<= 1) {
        float v = __shfl_up(S, ofs, 64);
        if (lane >= ofs) S += v;
      }
      float tot = __shfl(S, 63, 64);
      S += carry; carry += tot;
      float corr = 0.f;
      {
        unsigned int cws[8] = {c0.x,c0.y,c0.z,c0.w, c1.x,c1.y,c1.z,c1.w};
#pragma unroll
        for (int j = 0; j < 8; j++) {
          float Ca = __uint_as_float(cws[j] << 16);
          float Cb = __uint_as_float(cws[j] & 0xFFFF0000u);
          corr = fmaf(Ca * Hn[2*j],   __expf(A_[2*j]   * S), corr);
          corr = fmaf(Cb * Hn[2*j+1], __expf(A_[2*j+1] * S), corr);
        }
      }
      float zr = b2f(xz[(size_t)pmap(br, t) * E2 + DI + d]);
      float z = zr / (1.f + __expf(-zr));
      float y = corr * z * wef;
      red[w][lane] = y;
      __syncthreads();
      if (w == 0) {
        float ytot = red[0][lane] + red[1][lane] + red[2][lane] + red[3][lane];
        atomicAdd(srow + omap(br, t), ytot);
      }
      __syncthreads();
    }
  }
}

// ---------------- K8: w_eff[d] = lin_w . out_proj_w[:,d]; zero score_acc ------
__global__ __launch_bounds__(256) void k_weff_init(const ushort_t* __restrict__ opwb,
    const ushort_t* __restrict__ lwb, float* __restrict__ weff, float* __restrict__ sc) {
  int i = blockIdx.x * 256 + threadIdx.x;
  if (i < DI) {
    float s = 0.f;
    for (int o = 0; o < DIMX; o++) s += b2f(lwb[o]) * b2f(opwb[(size_t)o * DI + i]);
    weff[i] = s;
  }
  int j = i - DI;
  if (j >= 0 && j < 2 * SEQ) sc[j] = 0.f;
}

// ---------------- K9: outputs (f32): group interp+sigmoid, individual ---------
__global__ __launch_bounds__(256) void k_out(const float* __restrict__ g0,
    const float* __restrict__ g1, const float* __restrict__ g2,
    const float* __restrict__ sc, const float* __restrict__ lbf,
    float* __restrict__ out) {
  int idx = blockIdx.x * 256 + threadIdx.x;
  if (idx < 3 * SEQ) {
    int j = idx / SEQ, t = idx % SEQ;
    const float* g = (j == 0) ? g0 : (j == 1) ? g1 : g2;
    float pos = t * ((float)(LGS - 1) / (float)(SEQ - 1));
    int i0 = (int)floorf(pos);
    if (i0 < 0) i0 = 0; if (i0 > LGS - 2) i0 = LGS - 2;
    float wt = pos - (float)i0;
    float v = g[i0] * (1.f - wt) + g[i0 + 1] * wt;
    out[idx] = 1.f / (1.f + __expf(-v));
  } else if (idx < 5 * SEQ) {
    float t = sc[idx - 3 * SEQ] + lbf[0];
    out[idx] = 1.f / (1.f + __expf(-t));
  }
}

extern "C" void kernel_launch(void* const* d_in, const int* in_sizes, int n_in,
                              void* d_out, int out_size, void* d_ws, size_t ws_size,
                              hipStream_t stream) {
  char* ws = (char*)d_ws;
  ushort_t* lwb   = (ushort_t*)(ws + OFF_LWB);
  float*    lngf  = (float*)(ws + OFF_LNGF);
  float*    lnbf  = (float*)(ws + OFF_LNBF);
  float*    lbf   = (float*)(ws + OFF_LBF);
  float*    cwf   = (float*)(ws + OFF_CWF);
  float*    cbf   = (float*)(ws + OFF_CBF);
  float*    dtbf  = (float*)(ws + OFF_DTBF);
  float*    alf   = (float*)(ws + OFF_ALF);
  float*    ddf   = (float*)(ws + OFF_DDF);
  float*    weff  = (float*)(ws + OFF_WEFF);
  float*    sc    = (float*)(ws + OFF_SC);
  ushort_t* dtwb  = (ushort_t*)(ws + OFF_DTWB);
  ushort_t* xpwb  = (ushort_t*)(ws + OFF_XPWB);
  ushort_t* opwb  = (ushort_t*)(ws + OFF_OPWB);
  ushort_t* inwb  = (ushort_t*)(ws + OFF_INWB);
  ushort_t* xd    = (ushort_t*)(ws + OFF_XD);
  ushort_t* xz    = (ushort_t*)(ws + OFF_XZ);
  ushort_t* uT    = (ushort_t*)(ws + OFF_UT);
  ushort_t* h     = (ushort_t*)(ws + OFF_H);
  float*    Hloc  = (float*)(ws + OFF_HLOC);
  float*    Hin   = (float*)(ws + OFF_HIN);
  float*    Stot  = (float*)(ws + OFF_STOT);
  float*    OUT   = (float*)d_out;

  Tab tab;
  int c = 0;
  tab.e[c++] = {d_in[3], inwb, E2 * DIMX, 0};
  tab.e[c++] = {d_in[4], opwb, DIMX * DI, 0};
  tab.e[c++] = {d_in[5], lwb, DIMX, 0};
  for (int br = 0; br < 3; br++) {
    int base = 10 + br * 7;
    tab.e[c++] = {d_in[base + 2], xpwb + (size_t)br * KXP * DI, KXP * DI, 0};
    tab.e[c++] = {d_in[base + 3], dtwb + (size_t)br * DI * DTR, DI * DTR, 0};
  }
  tab.e[c++] = {d_in[1], lngf, DIMX, 1};
  tab.e[c++] = {d_in[2], lnbf, DIMX, 1};
  tab.e[c++] = {d_in[6], lbf, 1, 1};
  for (int br = 0; br < 3; br++) {
    int base = 10 + br * 7;
    tab.e[c++] = {d_in[base + 0], cwf + (size_t)br * DI * 4, DI * 4, 1};
    tab.e[c++] = {d_in[base + 1], cbf + (size_t)br * DI, DI, 1};
    tab.e[c++] = {d_in[base + 4], dtbf + (size_t)br * DI, DI, 1};
    tab.e[c++] = {d_in[base + 5], alf + (size_t)br * DI * NST, DI * NST, 1};
    tab.e[c++] = {d_in[base + 6], ddf + (size_t)br * DI, DI, 1};
  }

  dim3 blk(256);
  k_import<<<dim3(64, c), blk, 0, stream>>>(tab, c);
  k_weff_init<<<44, blk, 0, stream>>>(opwb, lwb, weff, sc);
  for (int b = 0; b < 2; b++) {
    k_ln<<<1280, blk, 0, stream>>>((const float*)d_in[0], lngf, lnbf, h, b);
    k_inproj<<<dim3(40, 16), blk, 0, stream>>>(h, inwb, xz);
    for (int br = 0; br < 3; br++) {
      k_conv<<<dim3(80, 16), blk, 0, stream>>>(xz, cwf + (size_t)br * DI * 4,
                                               cbf + (size_t)br * DI,
                                               uT + (size_t)br * SEQ * DI, br);
      k_xdbl<<<40, blk, 0, stream>>>(uT + (size_t)br * SEQ * DI,
                                     xpwb + (size_t)br * KXP * DI,
                                     xd + (size_t)br * SEQ * KXP);
    }
    k_scan1<<<1536, blk, 0, stream>>>(xz, uT, xd, dtwb, dtbf, alf, ddf, weff,
                                      sc, Hloc, Stot, b);
    k_stitch<<<192, blk, 0, stream>>>(Stot, Hloc, alf, Hin);
    k_scan2<<<768, blk, 0, stream>>>(xz, xd, dtwb, dtbf, alf, weff, Hin, sc, b);
  }
  k_out<<<100, blk, 0, stream>>>((const float*)d_in[7], (const float*)d_in[8],
                                 (const float*)d_in[9], sc, lbf, OUT);
}

// Round 8
// 1185.401 us; speedup vs baseline: 3.1574x; 1.1635x over previous
//
#include <hip/hip_runtime.h>
#include <stdint.h>

#define SEQ  5120
#define DIMX 512
#define E2   2048
#define DI   1024
#define NST  16
#define DTR  32
#define KXP  64
#define LGS  2048
#define NSL  5
#define NSEG 8
#define SEGL 640

typedef unsigned short ushort_t;
typedef __attribute__((ext_vector_type(8))) __bf16 bf16x8;
typedef __attribute__((ext_vector_type(4))) float f32x4;

__device__ __forceinline__ float b2f(ushort_t u) {
  union { unsigned int i; float f; } v; v.i = ((unsigned int)u) << 16; return v.f;
}
__device__ __forceinline__ ushort_t f2b(float f) {
  union { float f; unsigned int i; } v; v.f = f;
  unsigned int u = v.i;
  return (ushort_t)((u + 0x7FFFu + ((u >> 16) & 1u)) >> 16);
}

#define AS1 __attribute__((address_space(1)))
#define AS3 __attribute__((address_space(3)))
__device__ __forceinline__ void glds16(const void* g, void* l) {
  __builtin_amdgcn_global_load_lds((const AS1 void*)g, (AS3 void*)l, 16, 0, 0);
}

__device__ __forceinline__ int pmap(int br, int t) {   // scan pos -> data pos
  return (br == 0) ? t : (br == 1) ? (SEQ - 1 - t) : ((t % NSL) * 1024 + t / NSL);
}
__device__ __forceinline__ int omap(int br, int t) {   // scan pos -> output pos
  return (br == 0) ? t : (br == 1) ? (SEQ - 1 - t) : ((t & 1023) * NSL + (t >> 10));
}

// ---------------- workspace layout (bytes) ------------------------------------
#define OFF_LWB   ((size_t)256)
#define OFF_LNGF  ((size_t)1280)
#define OFF_LNBF  ((size_t)3328)
#define OFF_LBF   ((size_t)5376)
#define OFF_CWF   ((size_t)5632)
#define OFF_CBF   ((size_t)54784)
#define OFF_DTBF  ((size_t)67072)
#define OFF_ALF   ((size_t)79360)
#define OFF_DDF   ((size_t)275968)
#define OFF_WEFF  ((size_t)288256)
#define OFF_SC    ((size_t)292352)
#define OFF_DTWB  ((size_t)333312)
#define OFF_XPWB  ((size_t)529920)
#define OFF_OPWB  ((size_t)923136)
#define OFF_INWB  ((size_t)1971712)
#define OFF_XD    ((size_t)4068864)     // 6 x 5120*64*2  = 3,932,160
#define OFF_XZ    ((size_t)8001024)     // 2 x 5120*2048*2 = 41,943,040
#define OFF_UT    ((size_t)49944064)    // 6 x 5120*1024*2 = 62,914,560
#define OFF_H     OFF_UT                // h (10 MB, both batches) nested; dead pre-conv
#define OFF_HLOC  ((size_t)112858624)   // 6*8*1024*16*4 = 3,145,728
#define OFF_HIN   ((size_t)116004352)   // 3,145,728
#define OFF_STOT  ((size_t)119150080)   // 6*8*1024*4 = 196,608
// total = 119,346,688 B (~113.8 MiB)

// ---------------- K0: batched import (f32 params -> ws, bf16 or f32) ----------
struct Ent { const void* s; void* d; int n; int fmt; };
struct Tab { Ent e[28]; };

__global__ __launch_bounds__(256) void k_import(Tab t, int cnt) {
  int id = blockIdx.y;
  if (id >= cnt) return;
  Ent E = t.e[id];
  int stride = gridDim.x * 256;
  const float* s = (const float*)E.s;
  if (E.fmt == 0) {
    ushort_t* dst = (ushort_t*)E.d;
    for (int i = blockIdx.x * 256 + threadIdx.x; i < E.n; i += stride) dst[i] = f2b(s[i]);
  } else {
    float* dst = (float*)E.d;
    for (int i = blockIdx.x * 256 + threadIdx.x; i < E.n; i += stride) dst[i] = s[i];
  }
}

// ---------------- K1: LayerNorm + ReLU -> h (bf16, both batches) --------------
__global__ __launch_bounds__(256) void k_ln(const float* __restrict__ x,
    const float* __restrict__ gam, const float* __restrict__ bet,
    ushort_t* __restrict__ h) {
  int token = blockIdx.x * 4 + (threadIdx.x >> 6);   // 0..10239
  int lane = threadIdx.x & 63;
  const float* row = x + (size_t)token * DIMX + lane * 8;
  float4 a0 = *(const float4*)(row);
  float4 a1 = *(const float4*)(row + 4);
  float v[8] = {a0.x,a0.y,a0.z,a0.w,a1.x,a1.y,a1.z,a1.w};
  float s = 0.f, ss = 0.f;
#pragma unroll
  for (int i = 0; i < 8; i++) { s += v[i]; ss += v[i]*v[i]; }
#pragma unroll
  for (int m = 1; m < 64; m <<= 1) { s += __shfl_xor(s, m, 64); ss += __shfl_xor(ss, m, 64); }
  float mean = s * (1.f / DIMX);
  float rs = rsqrtf(ss * (1.f / DIMX) - mean * mean + 1e-5f);
  ushort_t o[8];
#pragma unroll
  for (int i = 0; i < 8; i++) {
    float y = (v[i] - mean) * rs * gam[lane*8+i] + bet[lane*8+i];
    o[i] = f2b(fmaxf(y, 0.f));
  }
  ushort_t* orow = h + (size_t)token * DIMX + lane * 8;
  *(ushort4*)(orow)     = make_ushort4(o[0],o[1],o[2],o[3]);
  *(ushort4*)(orow + 4) = make_ushort4(o[4],o[5],o[6],o[7]);
}

// ---------------- K2: in_proj GEMM (M=10240): xz[bl][e] = h @ W^T -------------
__global__ __launch_bounds__(256) void k_inproj(const ushort_t* __restrict__ hA,
    const ushort_t* __restrict__ Wb, ushort_t* __restrict__ xz) {
  __shared__ ushort_t As[128*32];
  __shared__ ushort_t Bs[128*32];
  const int tid = threadIdx.x;
  const int w = tid >> 6, lane = tid & 63;
  const int wr = w >> 1, wc = w & 1;
  const int m0 = blockIdx.x * 128, n0 = blockIdx.y * 128;
  const int lrow = lane & 15, lko = (lane >> 4) * 8;
  f32x4 acc[4][4];
#pragma unroll
  for (int i = 0; i < 4; i++)
#pragma unroll
    for (int j = 0; j < 4; j++) acc[i][j] = (f32x4){0.f,0.f,0.f,0.f};
  for (int k0 = 0; k0 < DIMX; k0 += 32) {
    __syncthreads();
#pragma unroll
    for (int r = 0; r < 2; r++) {
      int e = r * 256 + tid;
      int row = e >> 2, seg = e & 3;
      glds16(hA + (size_t)(m0 + row) * DIMX + k0 + seg * 8, &As[row*32 + seg*8]);
      glds16(Wb + (size_t)(n0 + row) * DIMX + k0 + seg * 8, &Bs[row*32 + seg*8]);
    }
    __syncthreads();
    bf16x8 aF[4], bF[4];
#pragma unroll
    for (int i = 0; i < 4; i++)
      aF[i] = *(const bf16x8*)&As[(wr*64 + i*16 + lrow)*32 + lko];
#pragma unroll
    for (int j = 0; j < 4; j++)
      bF[j] = *(const bf16x8*)&Bs[(wc*64 + j*16 + lrow)*32 + lko];
#pragma unroll
    for (int i = 0; i < 4; i++)
#pragma unroll
      for (int j = 0; j < 4; j++)
        acc[i][j] = __builtin_amdgcn_mfma_f32_16x16x32_bf16(aF[i], bF[j], acc[i][j], 0, 0, 0);
  }
#pragma unroll
  for (int i = 0; i < 4; i++)
#pragma unroll
    for (int j = 0; j < 4; j++)
#pragma unroll
      for (int r = 0; r < 4; r++) {
        int m = m0 + wr*64 + i*16 + (lane>>4)*4 + r;
        int n = n0 + wc*64 + j*16 + lrow;
        xz[(size_t)m * E2 + n] = f2b(acc[i][j][r]);
      }
}

// ---------------- K4: causal depthwise conv + silu -> uT[ch][t][d] ------------
__global__ __launch_bounds__(256) void k_conv(const ushort_t* __restrict__ xz,
    const float* __restrict__ cwA, const float* __restrict__ cbA,
    ushort_t* __restrict__ uTa) {
  __shared__ ushort_t xs[67][64];
  int ch = blockIdx.z, br = ch >> 1, b = ch & 1;
  int t0 = blockIdx.x * 64, d0 = blockIdx.y * 64;
  int tid = threadIdx.x, col = tid & 63, rg = tid >> 6;
  const float* cw = cwA + (size_t)br * DI * 4;
  const float* cb = cbA + (size_t)br * DI;
#pragma unroll
  for (int i = 0; i < 17; i++) {
    int row = rg + i * 4;
    if (row < 67) {
      int tau = t0 - 3 + row;
      ushort_t val = 0;
      if (tau >= 0) val = xz[((size_t)b * SEQ + pmap(br, tau)) * E2 + d0 + col];
      xs[row][col] = val;
    }
  }
  __syncthreads();
  int d = d0 + col;
  float w0 = cw[d*4+0], w1 = cw[d*4+1], w2 = cw[d*4+2], w3 = cw[d*4+3];
  float bias = cb[d];
  ushort_t* uT = uTa + (size_t)ch * SEQ * DI;
#pragma unroll
  for (int i = 0; i < 16; i++) {
    int ti = rg + i * 4;
    float a = bias + w0*b2f(xs[ti][col]) + w1*b2f(xs[ti+1][col])
                   + w2*b2f(xs[ti+2][col]) + w3*b2f(xs[ti+3][col]);
    float val = a / (1.f + __expf(-a));
    uT[(size_t)(t0 + ti) * DI + d] = f2b(val);
  }
}

// ---------------- K5: x_dbl GEMM (64-row tiles): xd[ch][t][64] ----------------
__global__ __launch_bounds__(256) void k_xdbl(const ushort_t* __restrict__ uTa,
    const ushort_t* __restrict__ xpwA, ushort_t* __restrict__ xdA) {
  __shared__ ushort_t As[64*32];
  __shared__ ushort_t Bs[64*32];
  int ch = blockIdx.y, br = ch >> 1;
  const ushort_t* uT  = uTa  + (size_t)ch * SEQ * DI;
  const ushort_t* xpw = xpwA + (size_t)br * KXP * DI;
  ushort_t* xd = xdA + (size_t)ch * SEQ * KXP;
  int t0 = blockIdx.x * 64;
  int tid = threadIdx.x, w = tid >> 6, lane = tid & 63;
  int lrow = lane & 15, lko = (lane >> 4) * 8;
  int row = tid >> 2, seg = tid & 3;
  f32x4 acc[4];
#pragma unroll
  for (int j = 0; j < 4; j++) acc[j] = (f32x4){0.f,0.f,0.f,0.f};
  for (int k0 = 0; k0 < DI; k0 += 32) {
    __syncthreads();
    glds16(uT + (size_t)(t0 + row) * DI + k0 + seg * 8, &As[row*32 + seg*8]);
    glds16(xpw + (size_t)row * DI + k0 + seg * 8, &Bs[row*32 + seg*8]);
    __syncthreads();
    bf16x8 aF = *(const bf16x8*)&As[(w*16 + lrow)*32 + lko];
#pragma unroll
    for (int j = 0; j < 4; j++) {
      bf16x8 bF = *(const bf16x8*)&Bs[(j*16 + lrow)*32 + lko];
      acc[j] = __builtin_amdgcn_mfma_f32_16x16x32_bf16(aF, bF, acc[j], 0, 0, 0);
    }
  }
#pragma unroll
  for (int j = 0; j < 4; j++)
#pragma unroll
    for (int r = 0; r < 4; r++) {
      int t = t0 + w*16 + (lane>>4)*4 + r;
      xd[(size_t)t * KXP + j*16 + lrow] = f2b(acc[j][r]);
    }
}

// ---------------- K7a: segmented local scan (both batches) --------------------
// grid 3072 = ch(bid>>9) x seg((bid>>6)&7) x dblk(bid&63)
__global__ __launch_bounds__(256, 7) void k_scan1(
    const ushort_t* __restrict__ xz, const ushort_t* __restrict__ uTa,
    const ushort_t* __restrict__ xdA, const ushort_t* __restrict__ dtwb,
    const float* __restrict__ dtbf, const float* __restrict__ alf,
    const float* __restrict__ ddf, const float* __restrict__ weff,
    float* __restrict__ sc, float* __restrict__ Hloc, float* __restrict__ Stot) {
  __shared__ __align__(16) float xdS[4][16][68];
  __shared__ __align__(16) float dtwS[16][36];
  __shared__ float2 valsS[4][4][18];
  int bid = blockIdx.x;
  int dblk = bid & 63, seg = (bid >> 6) & 7, ch = bid >> 9;
  int br = ch >> 1, b = ch & 1;
  int tid = threadIdx.x, w = tid >> 6, lane = tid & 63, g = lane >> 4, n = lane & 15;
  int dloc = w * 4 + g;
  int d = dblk * 16 + dloc;
#pragma unroll
  for (int r = 0; r < 2; r++) {
    int idx = r * 256 + tid;
    int c = idx >> 5, j = idx & 31;
    dtwS[c][j] = b2f(dtwb[(size_t)br * (DI*DTR) + (size_t)(dblk*16 + c) * DTR + j]);
  }
  __syncthreads();
  float dtb_d = dtbf[br * DI + d];
  float Ap  = -__expf(alf[br * (DI*NST) + d * NST + n]);
  float Dd  = ddf[br * DI + d];
  float wef = weff[d];
  const ushort_t* ub  = uTa + (size_t)ch * SEQ * DI;
  const ushort_t* xdb = xdA + (size_t)ch * SEQ * KXP;
  float* srow = sc + (size_t)b * SEQ;
  float hst = 0.f, Sacc = 0.f;
  int kk = lane >> 2, q = lane & 3;
  int tbeg = seg * SEGL;
  for (int t0 = tbeg; t0 < tbeg + SEGL; t0 += 16) {
    {
      const ushort_t* rp = xdb + (size_t)(t0 + kk) * KXP + q * 16;
      ushort4 h0 = *(const ushort4*)(rp);
      ushort4 h1 = *(const ushort4*)(rp + 4);
      ushort4 h2 = *(const ushort4*)(rp + 8);
      ushort4 h3 = *(const ushort4*)(rp + 12);
      float* dst = &xdS[w][kk][q * 16];
      dst[0]=b2f(h0.x); dst[1]=b2f(h0.y); dst[2]=b2f(h0.z); dst[3]=b2f(h0.w);
      dst[4]=b2f(h1.x); dst[5]=b2f(h1.y); dst[6]=b2f(h1.z); dst[7]=b2f(h1.w);
      dst[8]=b2f(h2.x); dst[9]=b2f(h2.y); dst[10]=b2f(h2.z); dst[11]=b2f(h2.w);
      dst[12]=b2f(h3.x); dst[13]=b2f(h3.y); dst[14]=b2f(h3.z); dst[15]=b2f(h3.w);
    }
    int tau = t0 + n;
    float acc = dtb_d;
#pragma unroll
    for (int jj = 0; jj < 8; jj++) {
      float4 a  = *(const float4*)&xdS[w][n][jj * 4];
      float4 wv = *(const float4*)&dtwS[dloc][jj * 4];
      acc += a.x * wv.x + a.y * wv.y + a.z * wv.z + a.w * wv.w;
    }
    float dlt = (acc > 20.f) ? acc : log1pf(__expf(acc));
    Sacc += dlt;
    float u = b2f(ub[(size_t)tau * DI + d]);
    float zr = b2f(xz[((size_t)b * SEQ + pmap(br, tau)) * E2 + DI + d]);
    float z = zr / (1.f + __expf(-zr));
    float gate = z * wef;
    float dug = Dd * u * gate;
    valsS[w][g][n] = make_float2(dlt, dlt * u);
    float hC[16];
#pragma unroll
    for (int k = 0; k < 16; k++) {
      float2 v = valsS[w][g][k];
      float Bn = xdS[w][k][32 + n];
      float Cn = xdS[w][k][48 + n];
      hst = fmaf(__expf(v.x * Ap), hst, v.y * Bn);
      hC[k] = hst * Cn;
    }
    float a8[8], a4[4], a2[2], y;
#pragma unroll
    for (int j = 0; j < 8; j++) {
      float keep = (n & 8) ? hC[j+8] : hC[j];
      float send = (n & 8) ? hC[j]   : hC[j+8];
      a8[j] = keep + __shfl_xor(send, 8, 64);
    }
#pragma unroll
    for (int j = 0; j < 4; j++) {
      float keep = (n & 4) ? a8[j+4] : a8[j];
      float send = (n & 4) ? a8[j]   : a8[j+4];
      a4[j] = keep + __shfl_xor(send, 4, 64);
    }
#pragma unroll
    for (int j = 0; j < 2; j++) {
      float keep = (n & 2) ? a4[j+2] : a4[j];
      float send = (n & 2) ? a4[j]   : a4[j+2];
      a2[j] = keep + __shfl_xor(send, 2, 64);
    }
    {
      float keep = (n & 1) ? a2[1] : a2[0];
      float send = (n & 1) ? a2[0] : a2[1];
      y = keep + __shfl_xor(send, 1, 64);
    }
    y = fmaf(y, gate, dug);
    y += __shfl_xor(y, 16, 64);
    y += __shfl_xor(y, 32, 64);
    if (lane < 16) atomicAdd(srow + omap(br, t0 + lane), y);
  }
  Hloc[(((size_t)ch * NSEG + seg) * 1024 + d) * 16 + n] = hst;
  Sacc += __shfl_xor(Sacc, 1, 64);
  Sacc += __shfl_xor(Sacc, 2, 64);
  Sacc += __shfl_xor(Sacc, 4, 64);
  Sacc += __shfl_xor(Sacc, 8, 64);
  if (n == 0) Stot[((size_t)ch * NSEG + seg) * 1024 + d] = Sacc;
}

// ---------------- K7b: stitch segment states ----------------------------------
__global__ __launch_bounds__(256) void k_stitch(const float* __restrict__ Stot,
    const float* __restrict__ Hloc, const float* __restrict__ alf,
    float* __restrict__ Hin) {
  int idx = blockIdx.x * 256 + threadIdx.x;     // 98304 = 6*1024*16
  int ch = idx >> 14, rem = idx & 16383, d = rem >> 4, n = rem & 15;
  int br = ch >> 1;
  float A = -__expf(alf[(size_t)br * (DI*NST) + d * NST + n]);
  float h = 0.f;
  for (int s = 0; s < NSEG; s++) {
    size_t base = ((size_t)ch * NSEG + s) * 1024 + d;
    Hin[base * 16 + n] = h;
    h = __expf(A * Stot[base]) * h + Hloc[base * 16 + n];
  }
}

// ---------------- K7c: carry correction (parallel over t) ---------------------
// grid 1536 = ch(bid>>8) x chgrp(bid&255). wave w -> channel d = chgrp*4+w.
__global__ __launch_bounds__(256, 4) void k_scan2(
    const ushort_t* __restrict__ xz, const ushort_t* __restrict__ xdA,
    const ushort_t* __restrict__ dtwb, const float* __restrict__ dtbf,
    const float* __restrict__ alf, const float* __restrict__ weff,
    const float* __restrict__ Hin, float* __restrict__ sc) {
  __shared__ float red[4][72];
  int ch = blockIdx.x >> 8, cg = blockIdx.x & 255;
  int br = ch >> 1, b = ch & 1;
  int tid = threadIdx.x, w = tid >> 6, lane = tid & 63;
  int d = cg * 4 + w;
  const ushort_t* dwp = dtwb + (size_t)br * (DI*DTR) + (size_t)d * DTR;
  uint4 dq0 = *(const uint4*)(dwp), dq1 = *(const uint4*)(dwp + 8),
        dq2 = *(const uint4*)(dwp + 16), dq3 = *(const uint4*)(dwp + 24);
  float dw[32];
  {
    unsigned int wds[16] = {dq0.x,dq0.y,dq0.z,dq0.w, dq1.x,dq1.y,dq1.z,dq1.w,
                            dq2.x,dq2.y,dq2.z,dq2.w, dq3.x,dq3.y,dq3.z,dq3.w};
#pragma unroll
    for (int j = 0; j < 16; j++) {
      dw[2*j]   = __uint_as_float(wds[j] << 16);
      dw[2*j+1] = __uint_as_float(wds[j] & 0xFFFF0000u);
    }
  }
  float dtb_d = dtbf[br * DI + d];
  float A_[16];
#pragma unroll
  for (int nn = 0; nn < 16; nn++)
    A_[nn] = -__expf(alf[(size_t)br * (DI*NST) + d * NST + nn]);
  float wef = weff[d];
  const ushort_t* xdb = xdA + (size_t)ch * SEQ * KXP;
  float* srow = sc + (size_t)b * SEQ;
  for (int seg = 1; seg < NSEG; seg++) {
    float Hn[16];
    const float* hp = Hin + (((size_t)ch * NSEG + seg) * 1024 + d) * 16;
#pragma unroll
    for (int nn = 0; nn < 16; nn++) Hn[nn] = hp[nn];
    float carry = 0.f;
    for (int w0 = seg * SEGL; w0 < seg * SEGL + SEGL; w0 += 64) {
      int t = w0 + lane;
      const ushort_t* rp = xdb + (size_t)t * KXP;
      uint4 q0 = *(const uint4*)(rp),      q1 = *(const uint4*)(rp + 8),
            q2 = *(const uint4*)(rp + 16), q3 = *(const uint4*)(rp + 24);
      uint4 c0 = *(const uint4*)(rp + 48), c1 = *(const uint4*)(rp + 56);
      float acc = dtb_d;
      {
        unsigned int wds[16] = {q0.x,q0.y,q0.z,q0.w, q1.x,q1.y,q1.z,q1.w,
                                q2.x,q2.y,q2.z,q2.w, q3.x,q3.y,q3.z,q3.w};
#pragma unroll
        for (int j = 0; j < 16; j++) {
          acc = fmaf(__uint_as_float(wds[j] << 16),        dw[2*j],   acc);
          acc = fmaf(__uint_as_float(wds[j] & 0xFFFF0000u), dw[2*j+1], acc);
        }
      }
      float dlt = (acc > 20.f) ? acc : log1pf(__expf(acc));
      float S = dlt;
#pragma unroll
      for (int ofs = 1; ofs < 64; ofs <<= 1) {
        float v = __shfl_up(S, ofs, 64);
        if (lane >= ofs) S += v;
      }
      float tot = __shfl(S, 63, 64);
      S += carry; carry += tot;
      float corr = 0.f;
      {
        unsigned int cws[8] = {c0.x,c0.y,c0.z,c0.w, c1.x,c1.y,c1.z,c1.w};
#pragma unroll
        for (int j = 0; j < 8; j++) {
          float Ca = __uint_as_float(cws[j] << 16);
          float Cb = __uint_as_float(cws[j] & 0xFFFF0000u);
          corr = fmaf(Ca * Hn[2*j],   __expf(A_[2*j]   * S), corr);
          corr = fmaf(Cb * Hn[2*j+1], __expf(A_[2*j+1] * S), corr);
        }
      }
      float zr = b2f(xz[((size_t)b * SEQ + pmap(br, t)) * E2 + DI + d]);
      float z = zr / (1.f + __expf(-zr));
      float y = corr * z * wef;
      red[w][lane] = y;
      __syncthreads();
      if (w == 0) {
        float ytot = red[0][lane] + red[1][lane] + red[2][lane] + red[3][lane];
        atomicAdd(srow + omap(br, t), ytot);
      }
      __syncthreads();
    }
  }
}

// ---------------- K8: w_eff[d] = lin_w . out_proj_w[:,d]; zero score_acc ------
__global__ __launch_bounds__(256) void k_weff_init(const ushort_t* __restrict__ opwb,
    const ushort_t* __restrict__ lwb, float* __restrict__ weff, float* __restrict__ sc) {
  int i = blockIdx.x * 256 + threadIdx.x;
  if (i < DI) {
    float s = 0.f;
    for (int o = 0; o < DIMX; o++) s += b2f(lwb[o]) * b2f(opwb[(size_t)o * DI + i]);
    weff[i] = s;
  }
  int j = i - DI;
  if (j >= 0 && j < 2 * SEQ) sc[j] = 0.f;
}

// ---------------- K9: outputs (f32): group interp+sigmoid, individual ---------
__global__ __launch_bounds__(256) void k_out(const float* __restrict__ g0,
    const float* __restrict__ g1, const float* __restrict__ g2,
    const float* __restrict__ sc, const float* __restrict__ lbf,
    float* __restrict__ out) {
  int idx = blockIdx.x * 256 + threadIdx.x;
  if (idx < 3 * SEQ) {
    int j = idx / SEQ, t = idx % SEQ;
    const float* g = (j == 0) ? g0 : (j == 1) ? g1 : g2;
    float pos = t * ((float)(LGS - 1) / (float)(SEQ - 1));
    int i0 = (int)floorf(pos);
    if (i0 < 0) i0 = 0; if (i0 > LGS - 2) i0 = LGS - 2;
    float wt = pos - (float)i0;
    float v = g[i0] * (1.f - wt) + g[i0 + 1] * wt;
    out[idx] = 1.f / (1.f + __expf(-v));
  } else if (idx < 5 * SEQ) {
    float t = sc[idx - 3 * SEQ] + lbf[0];
    out[idx] = 1.f / (1.f + __expf(-t));
  }
}

extern "C" void kernel_launch(void* const* d_in, const int* in_sizes, int n_in,
                              void* d_out, int out_size, void* d_ws, size_t ws_size,
                              hipStream_t stream) {
  char* ws = (char*)d_ws;
  ushort_t* lwb   = (ushort_t*)(ws + OFF_LWB);
  float*    lngf  = (float*)(ws + OFF_LNGF);
  float*    lnbf  = (float*)(ws + OFF_LNBF);
  float*    lbf   = (float*)(ws + OFF_LBF);
  float*    cwf   = (float*)(ws + OFF_CWF);
  float*    cbf   = (float*)(ws + OFF_CBF);
  float*    dtbf  = (float*)(ws + OFF_DTBF);
  float*    alf   = (float*)(ws + OFF_ALF);
  float*    ddf   = (float*)(ws + OFF_DDF);
  float*    weff  = (float*)(ws + OFF_WEFF);
  float*    sc    = (float*)(ws + OFF_SC);
  ushort_t* dtwb  = (ushort_t*)(ws + OFF_DTWB);
  ushort_t* xpwb  = (ushort_t*)(ws + OFF_XPWB);
  ushort_t* opwb  = (ushort_t*)(ws + OFF_OPWB);
  ushort_t* inwb  = (ushort_t*)(ws + OFF_INWB);
  ushort_t* xd    = (ushort_t*)(ws + OFF_XD);
  ushort_t* xz    = (ushort_t*)(ws + OFF_XZ);
  ushort_t* uT    = (ushort_t*)(ws + OFF_UT);
  ushort_t* h     = (ushort_t*)(ws + OFF_H);
  float*    Hloc  = (float*)(ws + OFF_HLOC);
  float*    Hin   = (float*)(ws + OFF_HIN);
  float*    Stot  = (float*)(ws + OFF_STOT);
  float*    OUT   = (float*)d_out;

  Tab tab;
  int c = 0;
  tab.e[c++] = {d_in[3], inwb, E2 * DIMX, 0};
  tab.e[c++] = {d_in[4], opwb, DIMX * DI, 0};
  tab.e[c++] = {d_in[5], lwb, DIMX, 0};
  for (int br = 0; br < 3; br++) {
    int base = 10 + br * 7;
    tab.e[c++] = {d_in[base + 2], xpwb + (size_t)br * KXP * DI, KXP * DI, 0};
    tab.e[c++] = {d_in[base + 3], dtwb + (size_t)br * DI * DTR, DI * DTR, 0};
  }
  tab.e[c++] = {d_in[1], lngf, DIMX, 1};
  tab.e[c++] = {d_in[2], lnbf, DIMX, 1};
  tab.e[c++] = {d_in[6], lbf, 1, 1};
  for (int br = 0; br < 3; br++) {
    int base = 10 + br * 7;
    tab.e[c++] = {d_in[base + 0], cwf + (size_t)br * DI * 4, DI * 4, 1};
    tab.e[c++] = {d_in[base + 1], cbf + (size_t)br * DI, DI, 1};
    tab.e[c++] = {d_in[base + 4], dtbf + (size_t)br * DI, DI, 1};
    tab.e[c++] = {d_in[base + 5], alf + (size_t)br * DI * NST, DI * NST, 1};
    tab.e[c++] = {d_in[base + 6], ddf + (size_t)br * DI, DI, 1};
  }

  dim3 blk(256);
  k_import<<<dim3(64, c), blk, 0, stream>>>(tab, c);
  k_weff_init<<<44, blk, 0, stream>>>(opwb, lwb, weff, sc);
  k_ln<<<2560, blk, 0, stream>>>((const float*)d_in[0], lngf, lnbf, h);
  k_inproj<<<dim3(80, 16), blk, 0, stream>>>(h, inwb, xz);
  k_conv<<<dim3(80, 16, 6), blk, 0, stream>>>(xz, cwf, cbf, uT);
  k_xdbl<<<dim3(80, 6), blk, 0, stream>>>(uT, xpwb, xd);
  k_scan1<<<3072, blk, 0, stream>>>(xz, uT, xd, dtwb, dtbf, alf, ddf, weff,
                                    sc, Hloc, Stot);
  k_stitch<<<384, blk, 0, stream>>>(Stot, Hloc, alf, Hin);
  k_scan2<<<1536, blk, 0, stream>>>(xz, xd, dtwb, dtbf, alf, weff, Hin, sc);
  k_out<<<100, blk, 0, stream>>>((const float*)d_in[7], (const float*)d_in[8],
                                 (const float*)d_in[9], sc, lbf, OUT);
}

// Round 9
// 1108.786 us; speedup vs baseline: 3.3756x; 1.0691x over previous
//
#include <hip/hip_runtime.h>
#include <stdint.h>

#define SEQ  5120
#define DIMX 512
#define E2   2048
#define DI   1024
#define NST  16
#define DTR  32
#define KXP  64
#define LGS  2048
#define NSL  5
#define NSEG 8
#define SEGL 640

typedef unsigned short ushort_t;
typedef __attribute__((ext_vector_type(8))) __bf16 bf16x8;
typedef __attribute__((ext_vector_type(4))) float f32x4;

__device__ __forceinline__ float b2f(ushort_t u) {
  union { unsigned int i; float f; } v; v.i = ((unsigned int)u) << 16; return v.f;
}
__device__ __forceinline__ ushort_t f2b(float f) {
  union { float f; unsigned int i; } v; v.f = f;
  unsigned int u = v.i;
  return (ushort_t)((u + 0x7FFFu + ((u >> 16) & 1u)) >> 16);
}

#define AS1 __attribute__((address_space(1)))
#define AS3 __attribute__((address_space(3)))
__device__ __forceinline__ void glds16(const void* g, void* l) {
  __builtin_amdgcn_global_load_lds((const AS1 void*)g, (AS3 void*)l, 16, 0, 0);
}

__device__ __forceinline__ int pmap(int br, int t) {   // scan pos -> data pos
  return (br == 0) ? t : (br == 1) ? (SEQ - 1 - t) : ((t % NSL) * 1024 + t / NSL);
}
__device__ __forceinline__ int omap(int br, int t) {   // scan pos -> output pos
  return (br == 0) ? t : (br == 1) ? (SEQ - 1 - t) : ((t & 1023) * NSL + (t >> 10));
}

// ---------------- workspace layout (bytes) ------------------------------------
#define OFF_LWB   ((size_t)256)
#define OFF_LNGF  ((size_t)1280)
#define OFF_LNBF  ((size_t)3328)
#define OFF_LBF   ((size_t)5376)
#define OFF_CWF   ((size_t)5632)
#define OFF_CBF   ((size_t)54784)
#define OFF_DTBF  ((size_t)67072)
#define OFF_ALF   ((size_t)79360)
#define OFF_DDF   ((size_t)275968)
#define OFF_WEFF  ((size_t)288256)
#define OFF_SC    ((size_t)292352)
#define OFF_DTWB  ((size_t)333312)
#define OFF_XPWB  ((size_t)529920)
#define OFF_OPWB  ((size_t)923136)
#define OFF_INWB  ((size_t)1971712)
#define OFF_DTWF  ((size_t)4068864)     // 3*1024*32*4 = 393,216
#define OFF_XD    ((size_t)4462080)     // 6*5120*64*2 = 3,932,160
#define OFF_XZ    ((size_t)8394240)     // 2*5120*2048*2 = 41,943,040
// overlays inside dead-xz region (xz dead after conv+zg):
#define OFF_BF    ((size_t)8394240)     // 6*16*5120*4 = 1,966,080
#define OFF_CF    ((size_t)10360320)    // 1,966,080
#define OFF_HLOC  ((size_t)12326400)    // 3,145,728
#define OFF_HIN   ((size_t)15472128)    // 3,145,728
#define OFF_STOT  ((size_t)18617856)    // 196,608
#define OFF_UB    ((size_t)50337280)    // 6*5120*1024*2 = 62,914,560 (blocked)
#define OFF_H     OFF_UB                // ln-out h nested; dead before conv
#define OFF_ZGB   ((size_t)113251840)   // 2*64*5120*16*2 = 20,971,520 (blocked)
// total = 134,223,360 B (~128 MiB)

// ---------------- K0: batched import (f32 params -> ws, bf16 or f32) ----------
struct Ent { const void* s; void* d; int n; int fmt; };
struct Tab { Ent e[32]; };

__global__ __launch_bounds__(256) void k_import(Tab t, int cnt) {
  int id = blockIdx.y;
  if (id >= cnt) return;
  Ent E = t.e[id];
  int stride = gridDim.x * 256;
  const float* s = (const float*)E.s;
  if (E.fmt == 0) {
    ushort_t* dst = (ushort_t*)E.d;
    for (int i = blockIdx.x * 256 + threadIdx.x; i < E.n; i += stride) dst[i] = f2b(s[i]);
  } else {
    float* dst = (float*)E.d;
    for (int i = blockIdx.x * 256 + threadIdx.x; i < E.n; i += stride) dst[i] = s[i];
  }
}

// ---------------- K1: LayerNorm + ReLU -> h (bf16, both batches) --------------
__global__ __launch_bounds__(256) void k_ln(const float* __restrict__ x,
    const float* __restrict__ gam, const float* __restrict__ bet,
    ushort_t* __restrict__ h) {
  int token = blockIdx.x * 4 + (threadIdx.x >> 6);
  int lane = threadIdx.x & 63;
  const float* row = x + (size_t)token * DIMX + lane * 8;
  float4 a0 = *(const float4*)(row);
  float4 a1 = *(const float4*)(row + 4);
  float v[8] = {a0.x,a0.y,a0.z,a0.w,a1.x,a1.y,a1.z,a1.w};
  float s = 0.f, ss = 0.f;
#pragma unroll
  for (int i = 0; i < 8; i++) { s += v[i]; ss += v[i]*v[i]; }
#pragma unroll
  for (int m = 1; m < 64; m <<= 1) { s += __shfl_xor(s, m, 64); ss += __shfl_xor(ss, m, 64); }
  float mean = s * (1.f / DIMX);
  float rs = rsqrtf(ss * (1.f / DIMX) - mean * mean + 1e-5f);
  ushort_t o[8];
#pragma unroll
  for (int i = 0; i < 8; i++) {
    float y = (v[i] - mean) * rs * gam[lane*8+i] + bet[lane*8+i];
    o[i] = f2b(fmaxf(y, 0.f));
  }
  ushort_t* orow = h + (size_t)token * DIMX + lane * 8;
  *(ushort4*)(orow)     = make_ushort4(o[0],o[1],o[2],o[3]);
  *(ushort4*)(orow + 4) = make_ushort4(o[4],o[5],o[6],o[7]);
}

// ---------------- K2: in_proj GEMM (M=10240): xz[bl][e] = h @ W^T -------------
__global__ __launch_bounds__(256) void k_inproj(const ushort_t* __restrict__ hA,
    const ushort_t* __restrict__ Wb, ushort_t* __restrict__ xz) {
  __shared__ ushort_t As[128*32];
  __shared__ ushort_t Bs[128*32];
  const int tid = threadIdx.x;
  const int w = tid >> 6, lane = tid & 63;
  const int wr = w >> 1, wc = w & 1;
  const int m0 = blockIdx.x * 128, n0 = blockIdx.y * 128;
  const int lrow = lane & 15, lko = (lane >> 4) * 8;
  f32x4 acc[4][4];
#pragma unroll
  for (int i = 0; i < 4; i++)
#pragma unroll
    for (int j = 0; j < 4; j++) acc[i][j] = (f32x4){0.f,0.f,0.f,0.f};
  for (int k0 = 0; k0 < DIMX; k0 += 32) {
    __syncthreads();
#pragma unroll
    for (int r = 0; r < 2; r++) {
      int e = r * 256 + tid;
      int row = e >> 2, seg = e & 3;
      glds16(hA + (size_t)(m0 + row) * DIMX + k0 + seg * 8, &As[row*32 + seg*8]);
      glds16(Wb + (size_t)(n0 + row) * DIMX + k0 + seg * 8, &Bs[row*32 + seg*8]);
    }
    __syncthreads();
    bf16x8 aF[4], bF[4];
#pragma unroll
    for (int i = 0; i < 4; i++)
      aF[i] = *(const bf16x8*)&As[(wr*64 + i*16 + lrow)*32 + lko];
#pragma unroll
    for (int j = 0; j < 4; j++)
      bF[j] = *(const bf16x8*)&Bs[(wc*64 + j*16 + lrow)*32 + lko];
#pragma unroll
    for (int i = 0; i < 4; i++)
#pragma unroll
      for (int j = 0; j < 4; j++)
        acc[i][j] = __builtin_amdgcn_mfma_f32_16x16x32_bf16(aF[i], bF[j], acc[i][j], 0, 0, 0);
  }
#pragma unroll
  for (int i = 0; i < 4; i++)
#pragma unroll
    for (int j = 0; j < 4; j++)
#pragma unroll
      for (int r = 0; r < 4; r++) {
        int m = m0 + wr*64 + i*16 + (lane>>4)*4 + r;
        int n = n0 + wc*64 + j*16 + lrow;
        xz[(size_t)m * E2 + n] = f2b(acc[i][j][r]);
      }
}

// ---------------- K4: conv + silu -> uB[ch][d>>4][t][16] (blocked) ------------
__global__ __launch_bounds__(256) void k_conv(const ushort_t* __restrict__ xz,
    const float* __restrict__ cwA, const float* __restrict__ cbA,
    ushort_t* __restrict__ uB) {
  __shared__ ushort_t xs[67][64];
  int ch = blockIdx.z, br = ch >> 1, b = ch & 1;
  int t0 = blockIdx.x * 64, d0 = blockIdx.y * 64;
  int tid = threadIdx.x, col = tid & 63, rg = tid >> 6;
  const float* cw = cwA + (size_t)br * DI * 4;
  const float* cb = cbA + (size_t)br * DI;
#pragma unroll
  for (int i = 0; i < 17; i++) {
    int row = rg + i * 4;
    if (row < 67) {
      int tau = t0 - 3 + row;
      ushort_t val = 0;
      if (tau >= 0) val = xz[((size_t)b * SEQ + pmap(br, tau)) * E2 + d0 + col];
      xs[row][col] = val;
    }
  }
  __syncthreads();
  int d = d0 + col;
  float w0 = cw[d*4+0], w1 = cw[d*4+1], w2 = cw[d*4+2], w3 = cw[d*4+3];
  float bias = cb[d];
  size_t dbbase = ((size_t)(ch * 64 + (d >> 4))) * SEQ;
#pragma unroll
  for (int i = 0; i < 16; i++) {
    int ti = rg + i * 4;
    float a = bias + w0*b2f(xs[ti][col]) + w1*b2f(xs[ti+1][col])
                   + w2*b2f(xs[ti+2][col]) + w3*b2f(xs[ti+3][col]);
    float val = a / (1.f + __expf(-a));
    uB[(dbbase + t0 + ti) * 16 + (col & 15)] = f2b(val);
  }
}

// ---------------- K4b: gate precompute -> zgB[b][d>>4][l][16] (blocked) -------
__global__ __launch_bounds__(256) void k_zg(const ushort_t* __restrict__ xz,
    const float* __restrict__ weff, ushort_t* __restrict__ zgB) {
  int b = blockIdx.z;
  int l0 = blockIdx.x * 64, d0 = blockIdx.y * 64;
  int tid = threadIdx.x, col = tid & 63, rg = tid >> 6;
  int d = d0 + col;
  float wef = weff[d];
  size_t dbbase = ((size_t)(b * 64 + (d >> 4))) * SEQ;
#pragma unroll
  for (int i = 0; i < 16; i++) {
    int l = l0 + rg + i * 4;
    float zr = b2f(xz[((size_t)b * SEQ + l) * E2 + DI + d]);
    float z = zr / (1.f + __expf(-zr));
    zgB[(dbbase + l) * 16 + (col & 15)] = f2b(z * wef);
  }
}

// ---------------- K5: x_dbl GEMM (reads blocked uB): xd[ch][t][64] ------------
__global__ __launch_bounds__(256) void k_xdbl(const ushort_t* __restrict__ uB,
    const ushort_t* __restrict__ xpwA, ushort_t* __restrict__ xdA) {
  __shared__ ushort_t As[64*32];
  __shared__ ushort_t Bs[64*32];
  int ch = blockIdx.y, br = ch >> 1;
  const ushort_t* xpw = xpwA + (size_t)br * KXP * DI;
  ushort_t* xd = xdA + (size_t)ch * SEQ * KXP;
  int t0 = blockIdx.x * 64;
  int tid = threadIdx.x, w = tid >> 6, lane = tid & 63;
  int lrow = lane & 15, lko = (lane >> 4) * 8;
  int row = tid >> 2, seg = tid & 3;
  f32x4 acc[4];
#pragma unroll
  for (int j = 0; j < 4; j++) acc[j] = (f32x4){0.f,0.f,0.f,0.f};
  for (int k0 = 0; k0 < DI; k0 += 32) {
    __syncthreads();
    glds16(uB + (((size_t)(ch*64 + (k0>>4) + (seg>>1)) * SEQ + t0 + row) * 16 + (seg&1)*8),
           &As[row*32 + seg*8]);
    glds16(xpw + (size_t)row * DI + k0 + seg * 8, &Bs[row*32 + seg*8]);
    __syncthreads();
    bf16x8 aF = *(const bf16x8*)&As[(w*16 + lrow)*32 + lko];
#pragma unroll
    for (int j = 0; j < 4; j++) {
      bf16x8 bF = *(const bf16x8*)&Bs[(j*16 + lrow)*32 + lko];
      acc[j] = __builtin_amdgcn_mfma_f32_16x16x32_bf16(aF, bF, acc[j], 0, 0, 0);
    }
  }
#pragma unroll
  for (int j = 0; j < 4; j++)
#pragma unroll
    for (int r = 0; r < 4; r++) {
      int t = t0 + w*16 + (lane>>4)*4 + r;
      xd[(size_t)t * KXP + j*16 + lrow] = f2b(acc[j][r]);
    }
}

// ---------------- K5b: expand xd B/C -> Bf/Cf[ch][n][t] f32 -------------------
__global__ __launch_bounds__(256) void k_bc(const ushort_t* __restrict__ xdA,
    float* __restrict__ Bf, float* __restrict__ Cf) {
  __shared__ float tb[128][34];
  int ch = blockIdx.y, t0 = blockIdx.x * 128;
  int tid = threadIdx.x;
  const ushort_t* xdb = xdA + (size_t)ch * SEQ * KXP;
#pragma unroll
  for (int i = 0; i < 2; i++) {
    int r = (tid >> 2) + i * 64;
    int q = tid & 3;
    const ushort_t* p = xdb + (size_t)(t0 + r) * KXP + 32 + q * 8;
    uint4 v = *(const uint4*)p;
    unsigned int wd[4] = {v.x, v.y, v.z, v.w};
    float* dst = &tb[r][q * 8];
#pragma unroll
    for (int j = 0; j < 4; j++) {
      dst[2*j]   = __uint_as_float(wd[j] << 16);
      dst[2*j+1] = __uint_as_float(wd[j] & 0xFFFF0000u);
    }
  }
  __syncthreads();
  int nn = tid >> 4, sg = tid & 15;
  float ob[8], oc[8];
#pragma unroll
  for (int j = 0; j < 8; j++) {
    ob[j] = tb[sg*8 + j][nn];
    oc[j] = tb[sg*8 + j][16 + nn];
  }
  float* Bp = Bf + ((size_t)ch * NST + nn) * SEQ + t0 + sg * 8;
  float* Cp = Cf + ((size_t)ch * NST + nn) * SEQ + t0 + sg * 8;
  *(float4*)Bp       = make_float4(ob[0],ob[1],ob[2],ob[3]);
  *(float4*)(Bp + 4) = make_float4(ob[4],ob[5],ob[6],ob[7]);
  *(float4*)Cp       = make_float4(oc[0],oc[1],oc[2],oc[3]);
  *(float4*)(Cp + 4) = make_float4(oc[4],oc[5],oc[6],oc[7]);
}

// ---------------- K7a: segmented local scan (lean-LDS version) ----------------
// grid 3072 = ch(bid>>9) x seg((bid>>6)&7) x dblk(bid&63)
__global__ __launch_bounds__(256, 4) void k_scan1(
    const ushort_t* __restrict__ xdA, const ushort_t* __restrict__ uB,
    const ushort_t* __restrict__ zgB, const float* __restrict__ Bf,
    const float* __restrict__ Cf, const float* __restrict__ dtwf,
    const float* __restrict__ dtbf, const float* __restrict__ alf,
    const float* __restrict__ ddf, float* __restrict__ sc,
    float* __restrict__ Hloc, float* __restrict__ Stot) {
  __shared__ __align__(16) float BS[4][16][18];
  __shared__ __align__(16) float CS[4][16][18];
  __shared__ float2 ddS[4][4][17];
  int bid = blockIdx.x;
  int dblk = bid & 63, seg = (bid >> 6) & 7, ch = bid >> 9;
  int br = ch >> 1, b = ch & 1;
  int tid = threadIdx.x, w = tid >> 6, lane = tid & 63, g = lane >> 4, n = lane & 15;
  int dloc = w * 4 + g;
  int d = dblk * 16 + dloc;
  float dtb_d = dtbf[br * DI + d];
  float Ap  = -__expf(alf[br * (DI*NST) + d * NST + n]);
  float Dd  = ddf[br * DI + d];
  const float* dwrow = dtwf + ((size_t)br * DI + d) * DTR;
  const ushort_t* xdb = xdA + (size_t)ch * SEQ * KXP;
  const ushort_t* uBp = uB  + ((size_t)(ch * 64 + dblk) * SEQ) * 16;
  const ushort_t* zgp = zgB + ((size_t)(b  * 64 + dblk) * SEQ) * 16;
  const float* Bfp = Bf + ((size_t)ch * NST) * SEQ;
  const float* Cfp = Cf + ((size_t)ch * NST) * SEQ;
  float* srow = sc + (size_t)b * SEQ;
  float hst = 0.f, Sacc = 0.f;
  int sn = lane >> 2, sq = lane & 3;
  for (int t0 = seg * SEGL; t0 < seg * SEGL + SEGL; t0 += 16) {
    // stage B,C tile (per wave, coalesced 16B/lane)
    *(float4*)&BS[w][sn][sq*4] = *(const float4*)&Bfp[(size_t)sn * SEQ + t0 + sq*4];
    *(float4*)&CS[w][sn][sq*4] = *(const float4*)&Cfp[(size_t)sn * SEQ + t0 + sq*4];
    // delta: per-lane dt row (L1-broadcast) dotted with dtw row (L1-broadcast)
    const ushort_t* rp = xdb + (size_t)(t0 + n) * KXP;
    uint4 q0 = *(const uint4*)(rp),      q1 = *(const uint4*)(rp + 8);
    uint4 q2 = *(const uint4*)(rp + 16), q3 = *(const uint4*)(rp + 24);
    float acc = dtb_d;
    {
      unsigned int wds[16] = {q0.x,q0.y,q0.z,q0.w, q1.x,q1.y,q1.z,q1.w,
                              q2.x,q2.y,q2.z,q2.w, q3.x,q3.y,q3.z,q3.w};
#pragma unroll
      for (int jj = 0; jj < 8; jj++) {
        float4 wv = *(const float4*)&dwrow[jj * 4];
        acc = fmaf(__uint_as_float(wds[2*jj]   << 16),         wv.x, acc);
        acc = fmaf(__uint_as_float(wds[2*jj]   & 0xFFFF0000u), wv.y, acc);
        acc = fmaf(__uint_as_float(wds[2*jj+1] << 16),         wv.z, acc);
        acc = fmaf(__uint_as_float(wds[2*jj+1] & 0xFFFF0000u), wv.w, acc);
      }
    }
    float dlt = (acc > 20.f) ? acc : log1pf(__expf(acc));
    Sacc += dlt;
    float u    = b2f(uBp[(size_t)(t0 + n) * 16 + dloc]);
    float gate = b2f(zgp[(size_t)pmap(br, t0 + n) * 16 + dloc]);
    float du  = dlt * u;
    float dug = Dd * u * gate;
    ddS[w][g][n] = make_float2(dlt, du);
    float Bk[16], Ck[16];
#pragma unroll
    for (int j = 0; j < 4; j++) {
      *(float4*)&Bk[j*4] = *(const float4*)&BS[w][n][j*4];
      *(float4*)&Ck[j*4] = *(const float4*)&CS[w][n][j*4];
    }
    float hC[16];
#pragma unroll
    for (int k = 0; k < 16; k++) {
      float2 v = ddS[w][g][k];
      hst = fmaf(__expf(v.x * Ap), hst, v.y * Bk[k]);
      hC[k] = hst * Ck[k];
    }
    float a8[8], a4[4], a2[2], y;
#pragma unroll
    for (int j = 0; j < 8; j++) {
      float keep = (n & 8) ? hC[j+8] : hC[j];
      float send = (n & 8) ? hC[j]   : hC[j+8];
      a8[j] = keep + __shfl_xor(send, 8, 64);
    }
#pragma unroll
    for (int j = 0; j < 4; j++) {
      float keep = (n & 4) ? a8[j+4] : a8[j];
      float send = (n & 4) ? a8[j]   : a8[j+4];
      a4[j] = keep + __shfl_xor(send, 4, 64);
    }
#pragma unroll
    for (int j = 0; j < 2; j++) {
      float keep = (n & 2) ? a4[j+2] : a4[j];
      float send = (n & 2) ? a4[j]   : a4[j+2];
      a2[j] = keep + __shfl_xor(send, 2, 64);
    }
    {
      float keep = (n & 1) ? a2[1] : a2[0];
      float send = (n & 1) ? a2[0] : a2[1];
      y = keep + __shfl_xor(send, 1, 64);
    }
    y = fmaf(y, gate, dug);
    y += __shfl_xor(y, 16, 64);
    y += __shfl_xor(y, 32, 64);
    if (lane < 16) atomicAdd(srow + omap(br, t0 + lane), y);
  }
  Hloc[(((size_t)ch * NSEG + seg) * 1024 + d) * 16 + n] = hst;
  Sacc += __shfl_xor(Sacc, 1, 64);
  Sacc += __shfl_xor(Sacc, 2, 64);
  Sacc += __shfl_xor(Sacc, 4, 64);
  Sacc += __shfl_xor(Sacc, 8, 64);
  if (n == 0) Stot[((size_t)ch * NSEG + seg) * 1024 + d] = Sacc;
}

// ---------------- K7b: stitch segment states ----------------------------------
__global__ __launch_bounds__(256) void k_stitch(const float* __restrict__ Stot,
    const float* __restrict__ Hloc, const float* __restrict__ alf,
    float* __restrict__ Hin) {
  int idx = blockIdx.x * 256 + threadIdx.x;     // 98304 = 6*1024*16
  int ch = idx >> 14, rem = idx & 16383, d = rem >> 4, n = rem & 15;
  int br = ch >> 1;
  float A = -__expf(alf[(size_t)br * (DI*NST) + d * NST + n]);
  float h = 0.f;
  for (int s = 0; s < NSEG; s++) {
    size_t base = ((size_t)ch * NSEG + s) * 1024 + d;
    Hin[base * 16 + n] = h;
    h = __expf(A * Stot[base]) * h + Hloc[base * 16 + n];
  }
}

// ---------------- K7c: carry correction (parallel over t) ---------------------
__global__ __launch_bounds__(256, 4) void k_scan2(
    const ushort_t* __restrict__ zgB, const ushort_t* __restrict__ xdA,
    const ushort_t* __restrict__ dtwb, const float* __restrict__ dtbf,
    const float* __restrict__ alf, const float* __restrict__ Hin,
    float* __restrict__ sc) {
  __shared__ float red[4][72];
  int ch = blockIdx.x >> 8, cg = blockIdx.x & 255;
  int br = ch >> 1, b = ch & 1;
  int tid = threadIdx.x, w = tid >> 6, lane = tid & 63;
  int d = cg * 4 + w;
  const ushort_t* dwp = dtwb + (size_t)br * (DI*DTR) + (size_t)d * DTR;
  uint4 dq0 = *(const uint4*)(dwp), dq1 = *(const uint4*)(dwp + 8),
        dq2 = *(const uint4*)(dwp + 16), dq3 = *(const uint4*)(dwp + 24);
  float dw[32];
  {
    unsigned int wds[16] = {dq0.x,dq0.y,dq0.z,dq0.w, dq1.x,dq1.y,dq1.z,dq1.w,
                            dq2.x,dq2.y,dq2.z,dq2.w, dq3.x,dq3.y,dq3.z,dq3.w};
#pragma unroll
    for (int j = 0; j < 16; j++) {
      dw[2*j]   = __uint_as_float(wds[j] << 16);
      dw[2*j+1] = __uint_as_float(wds[j] & 0xFFFF0000u);
    }
  }
  float dtb_d = dtbf[br * DI + d];
  float A_[16];
#pragma unroll
  for (int nn = 0; nn < 16; nn++)
    A_[nn] = -__expf(alf[(size_t)br * (DI*NST) + d * NST + nn]);
  const ushort_t* xdb = xdA + (size_t)ch * SEQ * KXP;
  const ushort_t* zgp = zgB + ((size_t)(b * 64 + (d >> 4)) * SEQ) * 16;
  int dsub = d & 15;
  float* srow = sc + (size_t)b * SEQ;
  for (int seg = 1; seg < NSEG; seg++) {
    float Hn[16];
    const float* hp = Hin + (((size_t)ch * NSEG + seg) * 1024 + d) * 16;
#pragma unroll
    for (int nn = 0; nn < 16; nn++) Hn[nn] = hp[nn];
    float carry = 0.f;
    for (int w0 = seg * SEGL; w0 < seg * SEGL + SEGL; w0 += 64) {
      int t = w0 + lane;
      const ushort_t* rp = xdb + (size_t)t * KXP;
      uint4 q0 = *(const uint4*)(rp),      q1 = *(const uint4*)(rp + 8),
            q2 = *(const uint4*)(rp + 16), q3 = *(const uint4*)(rp + 24);
      uint4 c0 = *(const uint4*)(rp + 48), c1 = *(const uint4*)(rp + 56);
      float acc = dtb_d;
      {
        unsigned int wds[16] = {q0.x,q0.y,q0.z,q0.w, q1.x,q1.y,q1.z,q1.w,
                                q2.x,q2.y,q2.z,q2.w, q3.x,q3.y,q3.z,q3.w};
#pragma unroll
        for (int j = 0; j < 16; j++) {
          acc = fmaf(__uint_as_float(wds[j] << 16),         dw[2*j],   acc);
          acc = fmaf(__uint_as_float(wds[j] & 0xFFFF0000u), dw[2*j+1], acc);
        }
      }
      float dlt = (acc > 20.f) ? acc : log1pf(__expf(acc));
      float S = dlt;
#pragma unroll
      for (int ofs = 1; ofs < 64; ofs <<= 1) {
        float v = __shfl_up(S, ofs, 64);
        if (lane >= ofs) S += v;
      }
      float tot = __shfl(S, 63, 64);
      S += carry; carry += tot;
      float corr = 0.f;
      {
        unsigned int cws[8] = {c0.x,c0.y,c0.z,c0.w, c1.x,c1.y,c1.z,c1.w};
#pragma unroll
        for (int j = 0; j < 8; j++) {
          float Ca = __uint_as_float(cws[j] << 16);
          float Cb = __uint_as_float(cws[j] & 0xFFFF0000u);
          corr = fmaf(Ca * Hn[2*j],   __expf(A_[2*j]   * S), corr);
          corr = fmaf(Cb * Hn[2*j+1], __expf(A_[2*j+1] * S), corr);
        }
      }
      float gate = b2f(zgp[(size_t)pmap(br, t) * 16 + dsub]);
      float y = corr * gate;
      red[w][lane] = y;
      __syncthreads();
      if (w == 0) {
        float ytot = red[0][lane] + red[1][lane] + red[2][lane] + red[3][lane];
        atomicAdd(srow + omap(br, t), ytot);
      }
      __syncthreads();
    }
  }
}

// ---------------- K8: w_eff[d] = lin_w . out_proj_w[:,d]; zero score_acc ------
__global__ __launch_bounds__(256) void k_weff_init(const ushort_t* __restrict__ opwb,
    const ushort_t* __restrict__ lwb, float* __restrict__ weff, float* __restrict__ sc) {
  int i = blockIdx.x * 256 + threadIdx.x;
  if (i < DI) {
    float s = 0.f;
    for (int o = 0; o < DIMX; o++) s += b2f(lwb[o]) * b2f(opwb[(size_t)o * DI + i]);
    weff[i] = s;
  }
  int j = i - DI;
  if (j >= 0 && j < 2 * SEQ) sc[j] = 0.f;
}

// ---------------- K9: outputs (f32): group interp+sigmoid, individual ---------
__global__ __launch_bounds__(256) void k_out(const float* __restrict__ g0,
    const float* __restrict__ g1, const float* __restrict__ g2,
    const float* __restrict__ sc, const float* __restrict__ lbf,
    float* __restrict__ out) {
  int idx = blockIdx.x * 256 + threadIdx.x;
  if (idx < 3 * SEQ) {
    int j = idx / SEQ, t = idx % SEQ;
    const float* g = (j == 0) ? g0 : (j == 1) ? g1 : g2;
    float pos = t * ((float)(LGS - 1) / (float)(SEQ - 1));
    int i0 = (int)floorf(pos);
    if (i0 < 0) i0 = 0; if (i0 > LGS - 2) i0 = LGS - 2;
    float wt = pos - (float)i0;
    float v = g[i0] * (1.f - wt) + g[i0 + 1] * wt;
    out[idx] = 1.f / (1.f + __expf(-v));
  } else if (idx < 5 * SEQ) {
    float t = sc[idx - 3 * SEQ] + lbf[0];
    out[idx] = 1.f / (1.f + __expf(-t));
  }
}

extern "C" void kernel_launch(void* const* d_in, const int* in_sizes, int n_in,
                              void* d_out, int out_size, void* d_ws, size_t ws_size,
                              hipStream_t stream) {
  char* ws = (char*)d_ws;
  ushort_t* lwb   = (ushort_t*)(ws + OFF_LWB);
  float*    lngf  = (float*)(ws + OFF_LNGF);
  float*    lnbf  = (float*)(ws + OFF_LNBF);
  float*    lbf   = (float*)(ws + OFF_LBF);
  float*    cwf   = (float*)(ws + OFF_CWF);
  float*    cbf   = (float*)(ws + OFF_CBF);
  float*    dtbf  = (float*)(ws + OFF_DTBF);
  float*    alf   = (float*)(ws + OFF_ALF);
  float*    ddf   = (float*)(ws + OFF_DDF);
  float*    weff  = (float*)(ws + OFF_WEFF);
  float*    sc    = (float*)(ws + OFF_SC);
  ushort_t* dtwb  = (ushort_t*)(ws + OFF_DTWB);
  float*    dtwf  = (float*)(ws + OFF_DTWF);
  ushort_t* xpwb  = (ushort_t*)(ws + OFF_XPWB);
  ushort_t* opwb  = (ushort_t*)(ws + OFF_OPWB);
  ushort_t* inwb  = (ushort_t*)(ws + OFF_INWB);
  ushort_t* xd    = (ushort_t*)(ws + OFF_XD);
  ushort_t* xz    = (ushort_t*)(ws + OFF_XZ);
  float*    Bf    = (float*)(ws + OFF_BF);
  float*    Cf    = (float*)(ws + OFF_CF);
  ushort_t* uB    = (ushort_t*)(ws + OFF_UB);
  ushort_t* h     = (ushort_t*)(ws + OFF_H);
  ushort_t* zgB   = (ushort_t*)(ws + OFF_ZGB);
  float*    Hloc  = (float*)(ws + OFF_HLOC);
  float*    Hin   = (float*)(ws + OFF_HIN);
  float*    Stot  = (float*)(ws + OFF_STOT);
  float*    OUT   = (float*)d_out;

  Tab tab;
  int c = 0;
  tab.e[c++] = {d_in[3], inwb, E2 * DIMX, 0};
  tab.e[c++] = {d_in[4], opwb, DIMX * DI, 0};
  tab.e[c++] = {d_in[5], lwb, DIMX, 0};
  for (int br = 0; br < 3; br++) {
    int base = 10 + br * 7;
    tab.e[c++] = {d_in[base + 2], xpwb + (size_t)br * KXP * DI, KXP * DI, 0};
    tab.e[c++] = {d_in[base + 3], dtwb + (size_t)br * DI * DTR, DI * DTR, 0};
    tab.e[c++] = {d_in[base + 3], dtwf + (size_t)br * DI * DTR, DI * DTR, 1};
  }
  tab.e[c++] = {d_in[1], lngf, DIMX, 1};
  tab.e[c++] = {d_in[2], lnbf, DIMX, 1};
  tab.e[c++] = {d_in[6], lbf, 1, 1};
  for (int br = 0; br < 3; br++) {
    int base = 10 + br * 7;
    tab.e[c++] = {d_in[base + 0], cwf + (size_t)br * DI * 4, DI * 4, 1};
    tab.e[c++] = {d_in[base + 1], cbf + (size_t)br * DI, DI, 1};
    tab.e[c++] = {d_in[base + 4], dtbf + (size_t)br * DI, DI, 1};
    tab.e[c++] = {d_in[base + 5], alf + (size_t)br * DI * NST, DI * NST, 1};
    tab.e[c++] = {d_in[base + 6], ddf + (size_t)br * DI, DI, 1};
  }

  dim3 blk(256);
  k_import<<<dim3(64, c), blk, 0, stream>>>(tab, c);
  k_weff_init<<<44, blk, 0, stream>>>(opwb, lwb, weff, sc);
  k_ln<<<2560, blk, 0, stream>>>((const float*)d_in[0], lngf, lnbf, h);
  k_inproj<<<dim3(80, 16), blk, 0, stream>>>(h, inwb, xz);
  k_conv<<<dim3(80, 16, 6), blk, 0, stream>>>(xz, cwf, cbf, uB);
  k_zg<<<dim3(80, 16, 2), blk, 0, stream>>>(xz, weff, zgB);
  k_xdbl<<<dim3(80, 6), blk, 0, stream>>>(uB, xpwb, xd);
  k_bc<<<dim3(40, 6), blk, 0, stream>>>(xd, Bf, Cf);
  k_scan1<<<3072, blk, 0, stream>>>(xd, uB, zgB, Bf, Cf, dtwf, dtbf, alf, ddf,
                                    sc, Hloc, Stot);
  k_stitch<<<384, blk, 0, stream>>>(Stot, Hloc, alf, Hin);
  k_scan2<<<1536, blk, 0, stream>>>(zgB, xd, dtwb, dtbf, alf, Hin, sc);
  k_out<<<100, blk, 0, stream>>>((const float*)d_in[7], (const float*)d_in[8],
                                 (const float*)d_in[9], sc, lbf, OUT);
}